// Round 2
// baseline (692.416 us; speedup 1.0000x reference)
//
#include <hip/hip_runtime.h>

// dims: B=16 W=32 M=512 NH=64 HALF=32 K=8 H=8 LK=16 LOUT=2 NSP=10 GCIN=24
// rows = B*M = 8192. Reference dtypes fp32; bf16 internally for MFMA.
// SINGLE regular dispatch, 512 blocks x 256 threads, manual global barrier
// (atomic counter in workspace, zeroed by captured hipMemsetAsync).
// Co-residency: __launch_bounds__(256,2) -> VGPR<=256 -> 2 blocks/CU; LDS
// 23.5KB -> 6/CU; waves -> 8/CU  =>  512 blocks all resident at t=0.
//   P0: rnn+e+conv+rg (blk<256) | WbT + nrmss=0 (blk>=256)
//   P1: amx, 2 tiles/block (verbatim body per tile)
//   P2: gemm_adjmix, 2 tiles/block (verbatim body per tile)
//   P3: gemm_h1 (+h1g), verbatim 32-row body, blocks<256 only
//   P4: ospout (+final proj), 16 rows/block

typedef __attribute__((ext_vector_type(8))) short bf16x8;
typedef __attribute__((ext_vector_type(4))) float f32x4;
#define MFMA16 __builtin_amdgcn_mfma_f32_16x16x32_bf16

#define NBLK 512u

__device__ __forceinline__ unsigned short f2bf(float f) {
    unsigned u = __float_as_uint(f);
    u += 0x7fff + ((u >> 16) & 1);          // RNE
    return (unsigned short)(u >> 16);
}
__device__ __forceinline__ float bf2f(unsigned short h) {
    return __uint_as_float(((unsigned)h) << 16);
}
__device__ __forceinline__ float fast_tanh(float x) {
    float e = __expf(2.f * x);
    return 1.f - 2.f / (e + 1.f);
}

// global barrier: release fence -> block barrier -> leader add+spin (agent
// scope) -> block barrier -> acquire fence. cnt is monotonic within one
// launch; target = NBLK * (phase index).
__device__ __forceinline__ void gbar(unsigned* cnt, unsigned target) {
    __threadfence();
    __syncthreads();
    if (threadIdx.x == 0) {
        __hip_atomic_fetch_add(cnt, 1u, __ATOMIC_ACQ_REL, __HIP_MEMORY_SCOPE_AGENT);
        while (__hip_atomic_load(cnt, __ATOMIC_ACQUIRE, __HIP_MEMORY_SCOPE_AGENT) < target)
            __builtin_amdgcn_s_sleep(2);
    }
    __syncthreads();
    __threadfence();
}

__global__ __launch_bounds__(256, 2) void cola_fused(
    const float* __restrict__ x, const float* __restrict__ adj,
    const float* __restrict__ Wih, const float* __restrict__ Whh,
    const float* __restrict__ bih, const float* __restrict__ bhh,
    const float* __restrict__ W1, const float* __restrict__ W2,
    const float* __restrict__ b1p, const float* __restrict__ Vp,
    const float* __restrict__ bvp, const float* __restrict__ Wb,
    const float* __restrict__ wbp, const float* __restrict__ conv_w,
    const float* __restrict__ conv_b, const float* __restrict__ convl_w,
    const float* __restrict__ convl_b, const float* __restrict__ gc1_w,
    const float* __restrict__ gc1_b, const float* __restrict__ gc2_w,
    const float* __restrict__ gc2_b, const float* __restrict__ out_w,
    const float* __restrict__ out_b, float* __restrict__ lh,
    float* __restrict__ e1, float* __restrict__ e2,
    float* __restrict__ nrmss, float* __restrict__ h1g,
    unsigned short* __restrict__ amxb, unsigned short* __restrict__ adjmixb,
    unsigned short* __restrict__ WbT, unsigned short* __restrict__ rgT,
    float* __restrict__ out, unsigned* cnt)
{
    __shared__ __align__(16) char smem[23552];
    const int blk = blockIdx.x;
    const int t = threadIdx.x;

    // ================= Phase 0: RNN+e+conv+rg | WbT | nrmss=0 =============
    if (blk < 256) {
        int wid = t >> 6, lane = t & 63;
        int rowblk = blk * 32;
        int b = rowblk >> 9, mb = rowblk & 511;
        float* xs = (float*)smem;                               // [32][32]
        unsigned short* hs = (unsigned short*)(smem + 4096);    // [2][16][72]
        float* rrs = (float*)(smem + 8704);                     // [32][25]

        for (int u = t; u < 1024; u += 256) {
            int tt = u >> 5, c = u & 31;
            xs[tt * 32 + c] = x[(b * 32 + tt) * 512 + mb + c];
        }
        for (int u = t; u < 2304; u += 256) hs[u] = 0;
        __syncthreads();

        if (wid < 2) {
            // RNN (waves 0,1; 16 series each)
            int l15 = lane & 15, quad = lane >> 4;
            int row0 = rowblk + wid * 16;
            unsigned short* hw0 = hs + wid * 1152;

            bf16x8 afr[4][2];
#pragma unroll
            for (int mt = 0; mt < 4; ++mt)
#pragma unroll
                for (int hf = 0; hf < 2; ++hf) {
                    const float* src = Whh + (16 * mt + l15) * 64 + 32 * hf + quad * 8;
                    union { bf16x8 v; unsigned short u[8]; } tmp;
#pragma unroll
                    for (int j = 0; j < 8; ++j) tmp.u[j] = f2bf(src[j]);
                    afr[mt][hf] = tmp.v;
                }
            bf16x8 wfr[2][2][2];
#pragma unroll
            for (int e = 0; e < 2; ++e)
#pragma unroll
                for (int nt = 0; nt < 2; ++nt)
#pragma unroll
                    for (int kf = 0; kf < 2; ++kf) {
                        const float* Wsrc = (e ? W2 : W1);
                        const float* src = Wsrc + (16 * nt + l15) * 64 + 32 * kf + quad * 8;
                        union { bf16x8 v; unsigned short u[8]; } tmp;
#pragma unroll
                        for (int j = 0; j < 8; ++j) tmp.u[j] = f2bf(src[j]);
                        wfr[e][nt][kf] = tmp.v;
                    }
            float wihv[4][4], bsv[4][4];
#pragma unroll
            for (int mt = 0; mt < 4; ++mt)
#pragma unroll
                for (int r = 0; r < 4; ++r) {
                    int n = 16 * mt + quad * 4 + r;
                    wihv[mt][r] = Wih[n];
                    bsv[mt][r]  = bih[n] + bhh[n];
                }

            float th[4][4];
            for (int tstep = 0; tstep < 32; ++tstep) {
                bf16x8 b0 = *(bf16x8*)(hw0 + l15 * 72 + quad * 8);
                bf16x8 b1 = *(bf16x8*)(hw0 + l15 * 72 + 32 + quad * 8);
                float xt = xs[tstep * 32 + wid * 16 + l15];
                f32x4 acc[4];
#pragma unroll
                for (int mt = 0; mt < 4; ++mt) {
                    f32x4 z = {0.f, 0.f, 0.f, 0.f};
                    acc[mt] = MFMA16(afr[mt][0], b0, z, 0, 0, 0);
                    acc[mt] = MFMA16(afr[mt][1], b1, acc[mt], 0, 0, 0);
                }
#pragma unroll
                for (int mt = 0; mt < 4; ++mt) {
                    ushort4 hwv;
#pragma unroll
                    for (int r = 0; r < 4; ++r)
                        th[mt][r] = fast_tanh(acc[mt][r] + xt * wihv[mt][r] + bsv[mt][r]);
                    hwv.x = f2bf(th[mt][0]); hwv.y = f2bf(th[mt][1]);
                    hwv.z = f2bf(th[mt][2]); hwv.w = f2bf(th[mt][3]);
                    *(ushort4*)(hw0 + l15 * 72 + 16 * mt + quad * 4) = hwv;
                }
            }
#pragma unroll
            for (int mt = 0; mt < 4; ++mt)
                *(float4*)(lh + (row0 + l15) * 64 + 16 * mt + quad * 4) =
                    make_float4(th[mt][0], th[mt][1], th[mt][2], th[mt][3]);

            bf16x8 a0 = *(bf16x8*)(hw0 + l15 * 72 + quad * 8);
            bf16x8 a1 = *(bf16x8*)(hw0 + l15 * 72 + 32 + quad * 8);
#pragma unroll
            for (int e = 0; e < 2; ++e) {
                float* dst = e ? e2 : e1;
#pragma unroll
                for (int nt = 0; nt < 2; ++nt) {
                    f32x4 z = {0.f, 0.f, 0.f, 0.f};
                    f32x4 ee = MFMA16(a0, wfr[e][nt][0], z, 0, 0, 0);
                    ee = MFMA16(a1, wfr[e][nt][1], ee, 0, 0, 0);
#pragma unroll
                    for (int r = 0; r < 4; ++r)
                        dst[(row0 + quad * 4 + r) * 32 + 16 * nt + l15] = ee[r];
                }
            }
        } else {
            // conv + rg (waves 2,3; 16 rows each)
            int wid2 = wid - 2;
#pragma unroll
            for (int rep = 0; rep < 2; ++rep) {
                int task = rep * 64 + lane;            // 128 tasks = 16 rows x 8 k
                int rl = wid2 * 16 + (task >> 3);
                int k  = task & 7;
                float s = conv_b[k];
                for (int w = 0; w < 32; ++w) s += xs[w * 32 + rl] * conv_w[k * 32 + w];
                float l0 = convl_b[k], l1 = l0;
                for (int tt = 0; tt < 16; ++tt) {
                    float wv = convl_w[k * 16 + tt];
                    l0 += xs[(2 * tt) * 32 + rl] * wv;
                    l1 += xs[(2 * tt + 1) * 32 + rl] * wv;
                }
                rrs[rl * 25 + k * 3 + 0] = fmaxf(s, 0.f);
                rrs[rl * 25 + k * 3 + 1] = fmaxf(l0, 0.f);
                rrs[rl * 25 + k * 3 + 2] = fmaxf(l1, 0.f);
            }
            __builtin_amdgcn_wave_barrier();
            int rl = wid2 * 16 + (lane & 15);
            int nb = lane >> 4;
#pragma unroll
            for (int q = 0; q < 16; ++q) {
                int n = nb * 16 + q;
                float acc = 0.f;
#pragma unroll
                for (int c = 0; c < 24; ++c) acc += rrs[rl * 25 + c] * gc1_w[c * 64 + n];
                rgT[b * 32768 + n * 512 + mb + rl] = f2bf(acc);
            }
        }
    } else {
        // Wb transpose (256 blocks) + nrmss zero (first 32 of them)
        int bid = blk - 256;
        if (bid < 32) nrmss[bid * 256 + t] = 0.f;
        int nb = (bid & 15) * 32, kb = (bid >> 4) * 32;
        float* tile = (float*)smem;             // [32][33]
        for (int u = t; u < 1024; u += 256) {
            int r = u >> 5, c = u & 31;
            tile[r * 33 + c] = Wb[(kb + r) * 512 + nb + c];
        }
        __syncthreads();
        for (int u = t; u < 1024; u += 256) {
            int r = u >> 5, c = u & 31;
            WbT[(nb + r) * 512 + kb + c] = f2bf(tile[c * 33 + r]);
        }
    }
    gbar(cnt, NBLK * 1u);

    // ================= Phase 1: amx, 2 tiles/block (verbatim body) ========
    {
        float (*e2s)[33] = (float (*)[33])smem;                 // 8448
        float (*e1s)[33] = (float (*)[33])(smem + 8448);        // 8448
        float* Vs        = (float*)(smem + 16896);              // 128
        float (*red)[68] = (float (*)[68])(smem + 17024);       // 4352
        const int ti = (t >> 4) * 4, tj = (t & 15) * 4;
        const float bv = bvp[0];
#pragma unroll 1
        for (int rep = 0; rep < 2; ++rep) {
            const int vt = blk * 2 + rep;
            const int bb = vt >> 6;
            const int i0 = ((vt >> 3) & 7) * 64;
            const int j0 = (vt & 7) * 64;
            __syncthreads();        // guard LDS overwrite vs prev rep reads
            for (int u = t; u < 2048; u += 256) {
                int r = u >> 5, c = u & 31;
                e2s[r][c] = e2[(bb * 512 + i0 + r) * 32 + c];
                e1s[r][c] = e1[(bb * 512 + j0 + r) * 32 + c] + b1p[c];
            }
            if (t < 32) Vs[t] = Vp[t];
            __syncthreads();
            float acc[4][4] = {};
#pragma unroll
            for (int h = 0; h < 32; ++h) {
                float vv = Vs[h];
                float xi[4], yj[4], Exi[4], Eyj[4];
#pragma unroll
                for (int p = 0; p < 4; ++p) { xi[p] = e2s[ti + p][h]; Exi[p] = __expf(xi[p]); }
#pragma unroll
                for (int q = 0; q < 4; ++q) { yj[q] = e1s[tj + q][h]; Eyj[q] = __expf(yj[q]); }
#pragma unroll
                for (int p = 0; p < 4; ++p)
#pragma unroll
                    for (int q = 0; q < 4; ++q) {
                        float v = xi[p] + yj[q];
                        float prod = Exi[p] * Eyj[q];
                        float el = v > 0.f ? v : prod - 1.f;  // exp(xi+yj)=Exi*Eyj
                        acc[p][q] += vv * el;
                    }
            }
            float ss[4] = {0.f, 0.f, 0.f, 0.f};
#pragma unroll
            for (int p = 0; p < 4; ++p) {
                float v0 = acc[p][0] + bv, v1 = acc[p][1] + bv;
                float v2 = acc[p][2] + bv, v3 = acc[p][3] + bv;
                ushort4 o;
                o.x = f2bf(v0); o.y = f2bf(v1); o.z = f2bf(v2); o.w = f2bf(v3);
                *(ushort4*)(amxb + (bb * 512 + i0 + ti + p) * 512 + j0 + tj) = o;
                ss[0] += v0 * v0; ss[1] += v1 * v1; ss[2] += v2 * v2; ss[3] += v3 * v3;
            }
#pragma unroll
            for (int q = 0; q < 4; ++q) red[t >> 4][tj + q] = ss[q];
            __syncthreads();
            if (t < 64) {
                float s = 0.f;
#pragma unroll
                for (int g = 0; g < 16; ++g) s += red[g][t];
                atomicAdd(&nrmss[bb * 512 + j0 + t], s);
            }
        }
    }
    gbar(cnt, NBLK * 2u);

    // ================= Phase 2: gemm_adjmix, 2 tiles/block (verbatim) =====
    {
        short* As = (short*)smem;               // 9216
        short* Bs = (short*)(smem + 9216);      // 9216
        float* rn = (float*)(smem + 18432);     // 2048
        const int w = t >> 6, lane = t & 63;
        const int l15 = lane & 15, quad = lane >> 4;
        const float wb = wbp[0];
#pragma unroll 1
        for (int rep = 0; rep < 2; ++rep) {
            const int vt = blk * 2 + rep;
            const int bb = vt >> 6;
            const int i0 = ((vt >> 3) & 7) * 64;
            const int j0 = (vt & 7) * 64;
            // idempotent across reps (same bb); ordered vs prev-rep reads by
            // the k-loop's barriers
            for (int u = t; u < 512; u += 256)
                rn[u] = 1.f / fmaxf(sqrtf(nrmss[bb * 512 + u]), 1e-12f);
            const unsigned short* Ag = amxb + bb * 262144;
            f32x4 acc[4] = {};
            for (int kk = 1; kk <= 8; ++kk) {
                int k0 = (j0 + 64 * kk) & 511;      // last iter: k0 == j0
                __syncthreads();
#pragma unroll
                for (int u0 = 0; u0 < 2; ++u0) {
                    int u = t + u0 * 256;
                    int i = u >> 3, o = u & 7;
                    *(int4*)(Bs + i * 72 + o * 8) =
                        *(const int4*)(WbT + (j0 + i) * 512 + k0 + o * 8);
                    union { int4 v; unsigned short us[8]; } ur;
                    ur.v = *(const int4*)(Ag + (i0 + i) * 512 + k0 + o * 8);
                    union { int4 v; unsigned short us[8]; } ow2;
#pragma unroll
                    for (int c = 0; c < 8; ++c)
                        ow2.us[c] = f2bf(bf2f(ur.us[c]) * rn[k0 + o * 8 + c]);
                    *(int4*)(As + i * 72 + o * 8) = ow2.v;
                }
                __syncthreads();
                bf16x8 a0 = *(bf16x8*)(As + (16 * w + l15) * 72 + quad * 8);
                bf16x8 a1 = *(bf16x8*)(As + (16 * w + l15) * 72 + 32 + quad * 8);
#pragma unroll
                for (int nt = 0; nt < 4; ++nt) {
                    bf16x8 b0 = *(bf16x8*)(Bs + (16 * nt + l15) * 72 + quad * 8);
                    bf16x8 b1 = *(bf16x8*)(Bs + (16 * nt + l15) * 72 + 32 + quad * 8);
                    acc[nt] = MFMA16(a0, b0, acc[nt], 0, 0, 0);
                    acc[nt] = MFMA16(a1, b1, acc[nt], 0, 0, 0);
                }
            }
            // As now holds scaled amx(i0:64, j0:64)
#pragma unroll
            for (int nt = 0; nt < 4; ++nt)
#pragma unroll
            for (int r = 0; r < 4; ++r) {
                int il = 16 * w + quad * 4 + r;
                int jl = 16 * nt + l15;
                int i = i0 + il, j = j0 + jl;
                float s  = acc[nt][r] + wb;
                float cv = 1.f / (1.f + __expf(-s));
                float am = bf2f((unsigned short)As[il * 72 + jl]);
                float ad = adj[i * 512 + j];
                adjmixb[(bb * 512 + i) * 512 + j] = f2bf(ad * cv + am * (1.f - cv));
            }
            // next rep's first k-iter __syncthreads orders As overwrite
        }
    }
    gbar(cnt, NBLK * 3u);

    // ================= Phase 3: gemm_h1 + h1g (verbatim, blocks<256) ======
    if (blk < 256) {
        short* As = (short*)smem;                           // 4608
        short* Bs = (short*)(smem + 4608);                  // 9216
        float (*h1s)[72] = (float (*)[72])(smem + 13824);   // 9216 -> 23040
        const int bb = blk >> 4;
        const int i0 = (blk & 15) * 32;
        const int w = t >> 6, lane = t & 63;
        const int l15 = lane & 15, quad = lane >> 4;
        const int rt = w & 1, ntb = (w >> 1) * 2;
        const unsigned short* Ag = adjmixb + bb * 262144;
        const unsigned short* Bg = rgT + bb * 32768;
        f32x4 acc[2] = {};
        for (int k0 = 0; k0 < 512; k0 += 64) {
            __syncthreads();
            {
                int i = t >> 3, o = t & 7;
                *(int4*)(As + i * 72 + o * 8) =
                    *(const int4*)(Ag + (i0 + i) * 512 + k0 + o * 8);
            }
#pragma unroll
            for (int u0 = 0; u0 < 2; ++u0) {
                int u = t + u0 * 256;
                int i = u >> 3, o = u & 7;
                *(int4*)(Bs + i * 72 + o * 8) =
                    *(const int4*)(Bg + i * 512 + k0 + o * 8);
            }
            __syncthreads();
            bf16x8 a0 = *(bf16x8*)(As + (16 * rt + l15) * 72 + quad * 8);
            bf16x8 a1 = *(bf16x8*)(As + (16 * rt + l15) * 72 + 32 + quad * 8);
#pragma unroll
            for (int q = 0; q < 2; ++q) {
                int nt = ntb + q;
                bf16x8 b0 = *(bf16x8*)(Bs + (16 * nt + l15) * 72 + quad * 8);
                bf16x8 b1 = *(bf16x8*)(Bs + (16 * nt + l15) * 72 + 32 + quad * 8);
                acc[q] = MFMA16(a0, b0, acc[q], 0, 0, 0);
                acc[q] = MFMA16(a1, b1, acc[q], 0, 0, 0);
            }
        }
#pragma unroll
        for (int q = 0; q < 2; ++q)
#pragma unroll
        for (int r = 0; r < 4; ++r) {
            int il = 16 * rt + quad * 4 + r;
            int j = 16 * (ntb + q) + l15;
            h1s[il][j] = fmaxf(acc[q][r] + gc1_b[j], 0.f);
        }
        __syncthreads();
        for (int u = t; u < 320; u += 256) {
            int row = u / 10, ns = u - row * 10;
            float a2 = 0.f;
#pragma unroll
            for (int j = 0; j < 64; ++j) a2 += h1s[row][j] * gc2_w[j * 10 + ns];
            h1g[(bb * 512 + i0 + row) * 10 + ns] = a2;
        }
    }
    gbar(cnt, NBLK * 4u);

    // ================= Phase 4: ospout (16 rows/block) =====================
    {
        float (*Bsm)[512] = (float (*)[512])smem;           // 20480
        float (*ow)[80]   = (float (*)[80])(smem + 20480);  // 2560
        float* ob  = (float*)(smem + 23040);                // 32
        float* g2b = (float*)(smem + 23072);                // 40
        const int r0 = blk * 16;
        const int bb = r0 >> 9;
        const int wid = t >> 6, lane = t & 63;
        for (int u = t; u < 5120; u += 256) {
            int k = u / 10, ns = u - k * 10;
            Bsm[ns][k] = h1g[bb * 5120 + u];
        }
        if (t < 8)  ob[t]  = out_b[t];
        if (t < 10) g2b[t] = gc2_b[t];
        for (int u = t; u < 592; u += 256) {
            int hh = u / 74, c = u - hh * 74;
            ow[hh][c] = out_w[u];
        }
        __syncthreads();
#pragma unroll
        for (int half = 0; half < 4; ++half) {
            int row = r0 + half * 4 + wid, m = row & 511;
            const unsigned short* Ar = adjmixb + row * 512;
            float a[8];
#pragma unroll
            for (int q = 0; q < 8; ++q) a[q] = bf2f(Ar[lane + 64 * q]);
            float os[10];
#pragma unroll
            for (int ns = 0; ns < 10; ++ns) {
                float s = 0.f;
#pragma unroll
                for (int q = 0; q < 8; ++q) s += a[q] * Bsm[ns][lane + 64 * q];
#pragma unroll
                for (int off = 32; off; off >>= 1) s += __shfl_xor(s, off);
                os[ns] = fmaxf(s + g2b[ns], 0.f);
            }
            float lv = lh[row * 64 + lane];
#pragma unroll
            for (int hh = 0; hh < 8; ++hh) {
                float t1 = lv * ow[hh][10 + lane];
#pragma unroll
                for (int off = 32; off; off >>= 1) t1 += __shfl_xor(t1, off);
                if (lane == hh) {
                    float acc = ob[hh] + t1;
#pragma unroll
                    for (int ns = 0; ns < 10; ++ns) acc += os[ns] * ow[hh][ns];
                    out[bb * 4096 + hh * 512 + m] = acc;
                }
            }
        }
    }
}

// ---------------- launch ---------------------------------------------------
extern "C" void kernel_launch(void* const* d_in, const int* in_sizes, int n_in,
                              void* d_out, int out_size, void* d_ws, size_t ws_size,
                              hipStream_t stream)
{
    const float* x       = (const float*)d_in[0];
    const float* adj     = (const float*)d_in[1];
    const float* Wih     = (const float*)d_in[2];
    const float* Whh     = (const float*)d_in[3];
    const float* bih     = (const float*)d_in[4];
    const float* bhh     = (const float*)d_in[5];
    const float* W1      = (const float*)d_in[6];
    const float* W2      = (const float*)d_in[7];
    const float* b1      = (const float*)d_in[8];
    const float* V       = (const float*)d_in[9];
    const float* bv      = (const float*)d_in[10];
    const float* Wb      = (const float*)d_in[11];
    const float* wb      = (const float*)d_in[12];
    const float* conv_w  = (const float*)d_in[13];
    const float* conv_b  = (const float*)d_in[14];
    const float* convl_w = (const float*)d_in[15];
    const float* convl_b = (const float*)d_in[16];
    const float* gc1_w   = (const float*)d_in[17];
    const float* gc1_b   = (const float*)d_in[18];
    const float* gc2_w   = (const float*)d_in[19];
    const float* gc2_b   = (const float*)d_in[20];
    const float* out_w   = (const float*)d_in[21];
    const float* out_b   = (const float*)d_in[22];

    float* ws    = (float*)d_ws;
    float* lh    = ws;                  // 524288 floats
    float* e1    = lh + 524288;         // 262144
    float* e2    = e1 + 262144;         // 262144
    float* nrmss = e2 + 262144;         // 8192
    float* h1g   = nrmss + 8192;        // 81920
    unsigned short* amxb    = (unsigned short*)(h1g + 81920);  // 4194304 shorts
    unsigned short* adjmixb = amxb + 4194304;                  // 4194304
    unsigned short* WbT     = adjmixb + 4194304;               // 262144
    unsigned short* rgT     = WbT + 262144;                    // 524288
    unsigned* cnt = (unsigned*)(rgT + 524288);                 // barrier counter
    float* outp = (float*)d_out;

    hipMemsetAsync(cnt, 0, 128, stream);
    cola_fused<<<512, 256, 0, stream>>>(
        x, adj, Wih, Whh, bih, bhh, W1, W2, b1, V, bv, Wb, wb,
        conv_w, conv_b, convl_w, convl_b, gc1_w, gc1_b, gc2_w, gc2_b,
        out_w, out_b, lh, e1, e2, nrmss, h1g, amxb, adjmixb, WbT, rgT,
        outp, cnt);
}

// Round 3
// 492.388 us; speedup vs baseline: 1.4062x; 1.4062x over previous
//
#include <hip/hip_runtime.h>

// dims: B=16 W=32 M=512 NH=64 HALF=32 K=8 H=8 LK=16 LOUT=2 NSP=10 GCIN=24
// rows = B*M = 8192. Reference dtypes fp32; bf16 internally for MFMA.
// SINGLE regular dispatch, 512 blocks x 256 threads, manual global barrier.
// R3 fix: spin loop polls with RELAXED atomic loads (NO buffer_inv per poll);
// release = leader-only threadfence+fetch_add(RELEASE); acquire = one
// threadfence after the spin. R2's ACQUIRE-in-loop emitted buffer_inv every
// poll iteration -> continuous chip-wide L1/L2 invalidation -> 550us stall.
// Co-residency: __launch_bounds__(256,2) -> 2 blocks/CU min; 512 blocks all
// resident at t=0 (proved by R2 passing).
//   P0: rnn+e+conv+rg (blk<256) | WbT + nrmss=0 (blk>=256)
//   P1: amx, 2 tiles/block
//   P2: gemm_adjmix, 2 tiles/block
//   P3: gemm_h1 (+h1g), blocks<256 only
//   P4: ospout (+final proj), 16 rows/block

typedef __attribute__((ext_vector_type(8))) short bf16x8;
typedef __attribute__((ext_vector_type(4))) float f32x4;
#define MFMA16 __builtin_amdgcn_mfma_f32_16x16x32_bf16

#define NBLK 512u

__device__ __forceinline__ unsigned short f2bf(float f) {
    unsigned u = __float_as_uint(f);
    u += 0x7fff + ((u >> 16) & 1);          // RNE
    return (unsigned short)(u >> 16);
}
__device__ __forceinline__ float bf2f(unsigned short h) {
    return __uint_as_float(((unsigned)h) << 16);
}
__device__ __forceinline__ float fast_tanh(float x) {
    float e = __expf(2.f * x);
    return 1.f - 2.f / (e + 1.f);
}

// Global barrier. Cache ops once per barrier, never in the poll loop:
//   __syncthreads()            -> compiler drains vmcnt(0) (stores acked to L2)
//   leader __threadfence()     -> L2 writeback (release), once per block
//   fetch_add(RELEASE)         -> publish arrival
//   spin on RELAXED loads      -> plain global_load, no cache maintenance
//   __syncthreads(); __threadfence() -> acquire-invalidate once per wave
__device__ __forceinline__ void gbar(unsigned* cnt, unsigned target) {
    __syncthreads();
    if (threadIdx.x == 0) {
        __threadfence();
        __hip_atomic_fetch_add(cnt, 1u, __ATOMIC_RELEASE, __HIP_MEMORY_SCOPE_AGENT);
        while (__hip_atomic_load(cnt, __ATOMIC_RELAXED, __HIP_MEMORY_SCOPE_AGENT) < target)
            __builtin_amdgcn_s_sleep(8);
    }
    __syncthreads();
    __threadfence();
}

__global__ __launch_bounds__(256, 2) void cola_fused(
    const float* __restrict__ x, const float* __restrict__ adj,
    const float* __restrict__ Wih, const float* __restrict__ Whh,
    const float* __restrict__ bih, const float* __restrict__ bhh,
    const float* __restrict__ W1, const float* __restrict__ W2,
    const float* __restrict__ b1p, const float* __restrict__ Vp,
    const float* __restrict__ bvp, const float* __restrict__ Wb,
    const float* __restrict__ wbp, const float* __restrict__ conv_w,
    const float* __restrict__ conv_b, const float* __restrict__ convl_w,
    const float* __restrict__ convl_b, const float* __restrict__ gc1_w,
    const float* __restrict__ gc1_b, const float* __restrict__ gc2_w,
    const float* __restrict__ gc2_b, const float* __restrict__ out_w,
    const float* __restrict__ out_b, float* __restrict__ lh,
    float* __restrict__ e1, float* __restrict__ e2,
    float* __restrict__ nrmss, float* __restrict__ h1g,
    unsigned short* __restrict__ amxb, unsigned short* __restrict__ adjmixb,
    unsigned short* __restrict__ WbT, unsigned short* __restrict__ rgT,
    float* __restrict__ out, unsigned* cnt)
{
    __shared__ __align__(16) char smem[23552];
    const int blk = blockIdx.x;
    const int t = threadIdx.x;

    // ================= Phase 0: RNN+e+conv+rg | WbT | nrmss=0 =============
    if (blk < 256) {
        int wid = t >> 6, lane = t & 63;
        int rowblk = blk * 32;
        int b = rowblk >> 9, mb = rowblk & 511;
        float* xs = (float*)smem;                               // [32][32]
        unsigned short* hs = (unsigned short*)(smem + 4096);    // [2][16][72]
        float* rrs = (float*)(smem + 8704);                     // [32][25]

        for (int u = t; u < 1024; u += 256) {
            int tt = u >> 5, c = u & 31;
            xs[tt * 32 + c] = x[(b * 32 + tt) * 512 + mb + c];
        }
        for (int u = t; u < 2304; u += 256) hs[u] = 0;
        __syncthreads();

        if (wid < 2) {
            // RNN (waves 0,1; 16 series each)
            int l15 = lane & 15, quad = lane >> 4;
            int row0 = rowblk + wid * 16;
            unsigned short* hw0 = hs + wid * 1152;

            bf16x8 afr[4][2];
#pragma unroll
            for (int mt = 0; mt < 4; ++mt)
#pragma unroll
                for (int hf = 0; hf < 2; ++hf) {
                    const float* src = Whh + (16 * mt + l15) * 64 + 32 * hf + quad * 8;
                    union { bf16x8 v; unsigned short u[8]; } tmp;
#pragma unroll
                    for (int j = 0; j < 8; ++j) tmp.u[j] = f2bf(src[j]);
                    afr[mt][hf] = tmp.v;
                }
            bf16x8 wfr[2][2][2];
#pragma unroll
            for (int e = 0; e < 2; ++e)
#pragma unroll
                for (int nt = 0; nt < 2; ++nt)
#pragma unroll
                    for (int kf = 0; kf < 2; ++kf) {
                        const float* Wsrc = (e ? W2 : W1);
                        const float* src = Wsrc + (16 * nt + l15) * 64 + 32 * kf + quad * 8;
                        union { bf16x8 v; unsigned short u[8]; } tmp;
#pragma unroll
                        for (int j = 0; j < 8; ++j) tmp.u[j] = f2bf(src[j]);
                        wfr[e][nt][kf] = tmp.v;
                    }
            float wihv[4][4], bsv[4][4];
#pragma unroll
            for (int mt = 0; mt < 4; ++mt)
#pragma unroll
                for (int r = 0; r < 4; ++r) {
                    int n = 16 * mt + quad * 4 + r;
                    wihv[mt][r] = Wih[n];
                    bsv[mt][r]  = bih[n] + bhh[n];
                }

            float th[4][4];
            for (int tstep = 0; tstep < 32; ++tstep) {
                bf16x8 b0 = *(bf16x8*)(hw0 + l15 * 72 + quad * 8);
                bf16x8 b1 = *(bf16x8*)(hw0 + l15 * 72 + 32 + quad * 8);
                float xt = xs[tstep * 32 + wid * 16 + l15];
                f32x4 acc[4];
#pragma unroll
                for (int mt = 0; mt < 4; ++mt) {
                    f32x4 z = {0.f, 0.f, 0.f, 0.f};
                    acc[mt] = MFMA16(afr[mt][0], b0, z, 0, 0, 0);
                    acc[mt] = MFMA16(afr[mt][1], b1, acc[mt], 0, 0, 0);
                }
#pragma unroll
                for (int mt = 0; mt < 4; ++mt) {
                    ushort4 hwv;
#pragma unroll
                    for (int r = 0; r < 4; ++r)
                        th[mt][r] = fast_tanh(acc[mt][r] + xt * wihv[mt][r] + bsv[mt][r]);
                    hwv.x = f2bf(th[mt][0]); hwv.y = f2bf(th[mt][1]);
                    hwv.z = f2bf(th[mt][2]); hwv.w = f2bf(th[mt][3]);
                    *(ushort4*)(hw0 + l15 * 72 + 16 * mt + quad * 4) = hwv;
                }
            }
#pragma unroll
            for (int mt = 0; mt < 4; ++mt)
                *(float4*)(lh + (row0 + l15) * 64 + 16 * mt + quad * 4) =
                    make_float4(th[mt][0], th[mt][1], th[mt][2], th[mt][3]);

            bf16x8 a0 = *(bf16x8*)(hw0 + l15 * 72 + quad * 8);
            bf16x8 a1 = *(bf16x8*)(hw0 + l15 * 72 + 32 + quad * 8);
#pragma unroll
            for (int e = 0; e < 2; ++e) {
                float* dst = e ? e2 : e1;
#pragma unroll
                for (int nt = 0; nt < 2; ++nt) {
                    f32x4 z = {0.f, 0.f, 0.f, 0.f};
                    f32x4 ee = MFMA16(a0, wfr[e][nt][0], z, 0, 0, 0);
                    ee = MFMA16(a1, wfr[e][nt][1], ee, 0, 0, 0);
#pragma unroll
                    for (int r = 0; r < 4; ++r)
                        dst[(row0 + quad * 4 + r) * 32 + 16 * nt + l15] = ee[r];
                }
            }
        } else {
            // conv + rg (waves 2,3; 16 rows each)
            int wid2 = wid - 2;
#pragma unroll
            for (int rep = 0; rep < 2; ++rep) {
                int task = rep * 64 + lane;            // 128 tasks = 16 rows x 8 k
                int rl = wid2 * 16 + (task >> 3);
                int k  = task & 7;
                float s = conv_b[k];
                for (int w = 0; w < 32; ++w) s += xs[w * 32 + rl] * conv_w[k * 32 + w];
                float l0 = convl_b[k], l1 = l0;
                for (int tt = 0; tt < 16; ++tt) {
                    float wv = convl_w[k * 16 + tt];
                    l0 += xs[(2 * tt) * 32 + rl] * wv;
                    l1 += xs[(2 * tt + 1) * 32 + rl] * wv;
                }
                rrs[rl * 25 + k * 3 + 0] = fmaxf(s, 0.f);
                rrs[rl * 25 + k * 3 + 1] = fmaxf(l0, 0.f);
                rrs[rl * 25 + k * 3 + 2] = fmaxf(l1, 0.f);
            }
            __builtin_amdgcn_wave_barrier();
            int rl = wid2 * 16 + (lane & 15);
            int nb = lane >> 4;
#pragma unroll
            for (int q = 0; q < 16; ++q) {
                int n = nb * 16 + q;
                float acc = 0.f;
#pragma unroll
                for (int c = 0; c < 24; ++c) acc += rrs[rl * 25 + c] * gc1_w[c * 64 + n];
                rgT[b * 32768 + n * 512 + mb + rl] = f2bf(acc);
            }
        }
    } else {
        // Wb transpose (256 blocks) + nrmss zero (first 32 of them)
        int bid = blk - 256;
        if (bid < 32) nrmss[bid * 256 + t] = 0.f;
        int nb = (bid & 15) * 32, kb = (bid >> 4) * 32;
        float* tile = (float*)smem;             // [32][33]
        for (int u = t; u < 1024; u += 256) {
            int r = u >> 5, c = u & 31;
            tile[r * 33 + c] = Wb[(kb + r) * 512 + nb + c];
        }
        __syncthreads();
        for (int u = t; u < 1024; u += 256) {
            int r = u >> 5, c = u & 31;
            WbT[(nb + r) * 512 + kb + c] = f2bf(tile[c * 33 + r]);
        }
    }
    gbar(cnt, NBLK * 1u);

    // ================= Phase 1: amx, 2 tiles/block ========================
    {
        float (*e2s)[33] = (float (*)[33])smem;                 // 8448
        float (*e1s)[33] = (float (*)[33])(smem + 8448);        // 8448
        float* Vs        = (float*)(smem + 16896);              // 128
        float (*red)[68] = (float (*)[68])(smem + 17024);       // 4352
        const int ti = (t >> 4) * 4, tj = (t & 15) * 4;
        const float bv = bvp[0];
#pragma unroll 1
        for (int rep = 0; rep < 2; ++rep) {
            const int vt = blk * 2 + rep;
            const int bb = vt >> 6;
            const int i0 = ((vt >> 3) & 7) * 64;
            const int j0 = (vt & 7) * 64;
            __syncthreads();        // guard LDS overwrite vs prev rep reads
            for (int u = t; u < 2048; u += 256) {
                int r = u >> 5, c = u & 31;
                e2s[r][c] = e2[(bb * 512 + i0 + r) * 32 + c];
                e1s[r][c] = e1[(bb * 512 + j0 + r) * 32 + c] + b1p[c];
            }
            if (t < 32) Vs[t] = Vp[t];
            __syncthreads();
            float acc[4][4] = {};
#pragma unroll
            for (int h = 0; h < 32; ++h) {
                float vv = Vs[h];
                float xi[4], yj[4], Exi[4], Eyj[4];
#pragma unroll
                for (int p = 0; p < 4; ++p) { xi[p] = e2s[ti + p][h]; Exi[p] = __expf(xi[p]); }
#pragma unroll
                for (int q = 0; q < 4; ++q) { yj[q] = e1s[tj + q][h]; Eyj[q] = __expf(yj[q]); }
#pragma unroll
                for (int p = 0; p < 4; ++p)
#pragma unroll
                    for (int q = 0; q < 4; ++q) {
                        float v = xi[p] + yj[q];
                        float prod = Exi[p] * Eyj[q];
                        float el = v > 0.f ? v : prod - 1.f;  // exp(xi+yj)=Exi*Eyj
                        acc[p][q] += vv * el;
                    }
            }
            float ss[4] = {0.f, 0.f, 0.f, 0.f};
#pragma unroll
            for (int p = 0; p < 4; ++p) {
                float v0 = acc[p][0] + bv, v1 = acc[p][1] + bv;
                float v2 = acc[p][2] + bv, v3 = acc[p][3] + bv;
                ushort4 o;
                o.x = f2bf(v0); o.y = f2bf(v1); o.z = f2bf(v2); o.w = f2bf(v3);
                *(ushort4*)(amxb + (bb * 512 + i0 + ti + p) * 512 + j0 + tj) = o;
                ss[0] += v0 * v0; ss[1] += v1 * v1; ss[2] += v2 * v2; ss[3] += v3 * v3;
            }
#pragma unroll
            for (int q = 0; q < 4; ++q) red[t >> 4][tj + q] = ss[q];
            __syncthreads();
            if (t < 64) {
                float s = 0.f;
#pragma unroll
                for (int g = 0; g < 16; ++g) s += red[g][t];
                atomicAdd(&nrmss[bb * 512 + j0 + t], s);
            }
        }
    }
    gbar(cnt, NBLK * 2u);

    // ================= Phase 2: gemm_adjmix, 2 tiles/block ================
    {
        short* As = (short*)smem;               // 9216
        short* Bs = (short*)(smem + 9216);      // 9216
        float* rn = (float*)(smem + 18432);     // 2048
        const int w = t >> 6, lane = t & 63;
        const int l15 = lane & 15, quad = lane >> 4;
        const float wb = wbp[0];
#pragma unroll 1
        for (int rep = 0; rep < 2; ++rep) {
            const int vt = blk * 2 + rep;
            const int bb = vt >> 6;
            const int i0 = ((vt >> 3) & 7) * 64;
            const int j0 = (vt & 7) * 64;
            // idempotent across reps (same bb); ordered vs prev-rep reads by
            // the k-loop's barriers
            for (int u = t; u < 512; u += 256)
                rn[u] = 1.f / fmaxf(sqrtf(nrmss[bb * 512 + u]), 1e-12f);
            const unsigned short* Ag = amxb + bb * 262144;
            f32x4 acc[4] = {};
            for (int kk = 1; kk <= 8; ++kk) {
                int k0 = (j0 + 64 * kk) & 511;      // last iter: k0 == j0
                __syncthreads();
#pragma unroll
                for (int u0 = 0; u0 < 2; ++u0) {
                    int u = t + u0 * 256;
                    int i = u >> 3, o = u & 7;
                    *(int4*)(Bs + i * 72 + o * 8) =
                        *(const int4*)(WbT + (j0 + i) * 512 + k0 + o * 8);
                    union { int4 v; unsigned short us[8]; } ur;
                    ur.v = *(const int4*)(Ag + (i0 + i) * 512 + k0 + o * 8);
                    union { int4 v; unsigned short us[8]; } ow2;
#pragma unroll
                    for (int c = 0; c < 8; ++c)
                        ow2.us[c] = f2bf(bf2f(ur.us[c]) * rn[k0 + o * 8 + c]);
                    *(int4*)(As + i * 72 + o * 8) = ow2.v;
                }
                __syncthreads();
                bf16x8 a0 = *(bf16x8*)(As + (16 * w + l15) * 72 + quad * 8);
                bf16x8 a1 = *(bf16x8*)(As + (16 * w + l15) * 72 + 32 + quad * 8);
#pragma unroll
                for (int nt = 0; nt < 4; ++nt) {
                    bf16x8 b0 = *(bf16x8*)(Bs + (16 * nt + l15) * 72 + quad * 8);
                    bf16x8 b1 = *(bf16x8*)(Bs + (16 * nt + l15) * 72 + 32 + quad * 8);
                    acc[nt] = MFMA16(a0, b0, acc[nt], 0, 0, 0);
                    acc[nt] = MFMA16(a1, b1, acc[nt], 0, 0, 0);
                }
            }
            // As now holds scaled amx(i0:64, j0:64)
#pragma unroll
            for (int nt = 0; nt < 4; ++nt)
#pragma unroll
            for (int r = 0; r < 4; ++r) {
                int il = 16 * w + quad * 4 + r;
                int jl = 16 * nt + l15;
                int i = i0 + il, j = j0 + jl;
                float s  = acc[nt][r] + wb;
                float cv = 1.f / (1.f + __expf(-s));
                float am = bf2f((unsigned short)As[il * 72 + jl]);
                float ad = adj[i * 512 + j];
                adjmixb[(bb * 512 + i) * 512 + j] = f2bf(ad * cv + am * (1.f - cv));
            }
            // next rep's first k-iter __syncthreads orders As overwrite
        }
    }
    gbar(cnt, NBLK * 3u);

    // ================= Phase 3: gemm_h1 + h1g (blocks<256) ================
    if (blk < 256) {
        short* As = (short*)smem;                           // 4608
        short* Bs = (short*)(smem + 4608);                  // 9216
        float (*h1s)[72] = (float (*)[72])(smem + 13824);   // 9216 -> 23040
        const int bb = blk >> 4;
        const int i0 = (blk & 15) * 32;
        const int w = t >> 6, lane = t & 63;
        const int l15 = lane & 15, quad = lane >> 4;
        const int rt = w & 1, ntb = (w >> 1) * 2;
        const unsigned short* Ag = adjmixb + bb * 262144;
        const unsigned short* Bg = rgT + bb * 32768;
        f32x4 acc[2] = {};
        for (int k0 = 0; k0 < 512; k0 += 64) {
            __syncthreads();
            {
                int i = t >> 3, o = t & 7;
                *(int4*)(As + i * 72 + o * 8) =
                    *(const int4*)(Ag + (i0 + i) * 512 + k0 + o * 8);
            }
#pragma unroll
            for (int u0 = 0; u0 < 2; ++u0) {
                int u = t + u0 * 256;
                int i = u >> 3, o = u & 7;
                *(int4*)(Bs + i * 72 + o * 8) =
                    *(const int4*)(Bg + i * 512 + k0 + o * 8);
            }
            __syncthreads();
            bf16x8 a0 = *(bf16x8*)(As + (16 * rt + l15) * 72 + quad * 8);
            bf16x8 a1 = *(bf16x8*)(As + (16 * rt + l15) * 72 + 32 + quad * 8);
#pragma unroll
            for (int q = 0; q < 2; ++q) {
                int nt = ntb + q;
                bf16x8 b0 = *(bf16x8*)(Bs + (16 * nt + l15) * 72 + quad * 8);
                bf16x8 b1 = *(bf16x8*)(Bs + (16 * nt + l15) * 72 + 32 + quad * 8);
                acc[q] = MFMA16(a0, b0, acc[q], 0, 0, 0);
                acc[q] = MFMA16(a1, b1, acc[q], 0, 0, 0);
            }
        }
#pragma unroll
        for (int q = 0; q < 2; ++q)
#pragma unroll
        for (int r = 0; r < 4; ++r) {
            int il = 16 * rt + quad * 4 + r;
            int j = 16 * (ntb + q) + l15;
            h1s[il][j] = fmaxf(acc[q][r] + gc1_b[j], 0.f);
        }
        __syncthreads();
        for (int u = t; u < 320; u += 256) {
            int row = u / 10, ns = u - row * 10;
            float a2 = 0.f;
#pragma unroll
            for (int j = 0; j < 64; ++j) a2 += h1s[row][j] * gc2_w[j * 10 + ns];
            h1g[(bb * 512 + i0 + row) * 10 + ns] = a2;
        }
    }
    gbar(cnt, NBLK * 4u);

    // ================= Phase 4: ospout (16 rows/block) =====================
    {
        float (*Bsm)[512] = (float (*)[512])smem;           // 20480
        float (*ow)[80]   = (float (*)[80])(smem + 20480);  // 2560
        float* ob  = (float*)(smem + 23040);                // 32
        float* g2b = (float*)(smem + 23072);                // 40
        const int r0 = blk * 16;
        const int bb = r0 >> 9;
        const int wid = t >> 6, lane = t & 63;
        for (int u = t; u < 5120; u += 256) {
            int k = u / 10, ns = u - k * 10;
            Bsm[ns][k] = h1g[bb * 5120 + u];
        }
        if (t < 8)  ob[t]  = out_b[t];
        if (t < 10) g2b[t] = gc2_b[t];
        for (int u = t; u < 592; u += 256) {
            int hh = u / 74, c = u - hh * 74;
            ow[hh][c] = out_w[u];
        }
        __syncthreads();
#pragma unroll
        for (int half = 0; half < 4; ++half) {
            int row = r0 + half * 4 + wid, m = row & 511;
            const unsigned short* Ar = adjmixb + row * 512;
            float a[8];
#pragma unroll
            for (int q = 0; q < 8; ++q) a[q] = bf2f(Ar[lane + 64 * q]);
            float os[10];
#pragma unroll
            for (int ns = 0; ns < 10; ++ns) {
                float s = 0.f;
#pragma unroll
                for (int q = 0; q < 8; ++q) s += a[q] * Bsm[ns][lane + 64 * q];
#pragma unroll
                for (int off = 32; off; off >>= 1) s += __shfl_xor(s, off);
                os[ns] = fmaxf(s + g2b[ns], 0.f);
            }
            float lv = lh[row * 64 + lane];
#pragma unroll
            for (int hh = 0; hh < 8; ++hh) {
                float t1 = lv * ow[hh][10 + lane];
#pragma unroll
                for (int off = 32; off; off >>= 1) t1 += __shfl_xor(t1, off);
                if (lane == hh) {
                    float acc = ob[hh] + t1;
#pragma unroll
                    for (int ns = 0; ns < 10; ++ns) acc += os[ns] * ow[hh][ns];
                    out[bb * 4096 + hh * 512 + m] = acc;
                }
            }
        }
    }
}

// ---------------- launch ---------------------------------------------------
extern "C" void kernel_launch(void* const* d_in, const int* in_sizes, int n_in,
                              void* d_out, int out_size, void* d_ws, size_t ws_size,
                              hipStream_t stream)
{
    const float* x       = (const float*)d_in[0];
    const float* adj     = (const float*)d_in[1];
    const float* Wih     = (const float*)d_in[2];
    const float* Whh     = (const float*)d_in[3];
    const float* bih     = (const float*)d_in[4];
    const float* bhh     = (const float*)d_in[5];
    const float* W1      = (const float*)d_in[6];
    const float* W2      = (const float*)d_in[7];
    const float* b1      = (const float*)d_in[8];
    const float* V       = (const float*)d_in[9];
    const float* bv      = (const float*)d_in[10];
    const float* Wb      = (const float*)d_in[11];
    const float* wb      = (const float*)d_in[12];
    const float* conv_w  = (const float*)d_in[13];
    const float* conv_b  = (const float*)d_in[14];
    const float* convl_w = (const float*)d_in[15];
    const float* convl_b = (const float*)d_in[16];
    const float* gc1_w   = (const float*)d_in[17];
    const float* gc1_b   = (const float*)d_in[18];
    const float* gc2_w   = (const float*)d_in[19];
    const float* gc2_b   = (const float*)d_in[20];
    const float* out_w   = (const float*)d_in[21];
    const float* out_b   = (const float*)d_in[22];

    float* ws    = (float*)d_ws;
    float* lh    = ws;                  // 524288 floats
    float* e1    = lh + 524288;         // 262144
    float* e2    = e1 + 262144;         // 262144
    float* nrmss = e2 + 262144;         // 8192
    float* h1g   = nrmss + 8192;        // 81920
    unsigned short* amxb    = (unsigned short*)(h1g + 81920);  // 4194304 shorts
    unsigned short* adjmixb = amxb + 4194304;                  // 4194304
    unsigned short* WbT     = adjmixb + 4194304;               // 262144
    unsigned short* rgT     = WbT + 262144;                    // 524288
    unsigned* cnt = (unsigned*)(rgT + 524288);                 // barrier counter
    float* outp = (float*)d_out;

    hipMemsetAsync(cnt, 0, 128, stream);
    cola_fused<<<512, 256, 0, stream>>>(
        x, adj, Wih, Whh, bih, bhh, W1, W2, b1, V, bv, Wb, wb,
        conv_w, conv_b, convl_w, convl_b, gc1_w, gc1_b, gc2_w, gc2_b,
        out_w, out_b, lh, e1, e2, nrmss, h1g, amxb, adjmixb, WbT, rgT,
        outp, cnt);
}

// Round 4
// 322.363 us; speedup vs baseline: 2.1479x; 1.5274x over previous
//
#include <hip/hip_runtime.h>

// dims: B=16 W=32 M=512 NH=64 HALF=32 K=8 H=8 LK=16 LOUT=2 NSP=10 GCIN=24
// rows = B*M = 8192. Reference dtypes fp32; bf16 internally for MFMA.
// SINGLE dispatch, 512 blocks x 256 threads, DISTRIBUTED global barrier:
//   arrive: leader release-stores phase to its OWN flag word (no RMW, no
//           same-line ping-pong across XCDs)
//   gather: block 0's 256 threads sweep all 512 flags in parallel
//   release: block 0 publishes one rel word; everyone polls it read-only
//   acquire: ONE __threadfence per block (wave 0; L1 is per-CU shared)
// R3's 90us/barrier = 512 same-line RMWs ping-ponging across 8 XCD L2s +
// per-wave acquire fences thrashing co-resident blocks' caches.
//   P0: rnn+e+conv+rg (blk<256) | WbT + nrmss=0 (blk>=256)
//   P1: amx, 2 tiles/block
//   P2: gemm_adjmix, 2 tiles/block
//   P3: gemm_h1 (+h1g), blocks<256 only
//   P4: ospout (+final proj), 16 rows/block

typedef __attribute__((ext_vector_type(8))) short bf16x8;
typedef __attribute__((ext_vector_type(4))) float f32x4;
#define MFMA16 __builtin_amdgcn_mfma_f32_16x16x32_bf16

__device__ __forceinline__ unsigned short f2bf(float f) {
    unsigned u = __float_as_uint(f);
    u += 0x7fff + ((u >> 16) & 1);          // RNE
    return (unsigned short)(u >> 16);
}
__device__ __forceinline__ float bf2f(unsigned short h) {
    return __uint_as_float(((unsigned)h) << 16);
}
__device__ __forceinline__ float fast_tanh(float x) {
    float e = __expf(2.f * x);
    return 1.f - 2.f / (e + 1.f);
}

// Distributed sense-free barrier. flags[512] + rel, all start at 0 (memset),
// phase is monotonically increasing 1..4 within the launch.
__device__ __forceinline__ void gbar(unsigned* flags, unsigned* rel, unsigned phase) {
    __syncthreads();                    // all waves drain vmcnt before signal
    if (blockIdx.x == 0) {
        const int t = threadIdx.x;
        if (t > 0) {                    // block 0 has no flag of its own
            while (__hip_atomic_load(&flags[t], __ATOMIC_RELAXED,
                                     __HIP_MEMORY_SCOPE_AGENT) < phase)
                __builtin_amdgcn_s_sleep(2);
        }
        while (__hip_atomic_load(&flags[t + 256], __ATOMIC_RELAXED,
                                 __HIP_MEMORY_SCOPE_AGENT) < phase)
            __builtin_amdgcn_s_sleep(2);
        __syncthreads();
        if (t == 0) {
            __threadfence();            // release block 0's own phase stores
            __hip_atomic_store(rel, phase, __ATOMIC_RELEASE,
                               __HIP_MEMORY_SCOPE_AGENT);
        }
    } else {
        if (threadIdx.x == 0) {
            __threadfence();            // release this block's phase stores
            __hip_atomic_store(&flags[blockIdx.x], phase, __ATOMIC_RELEASE,
                               __HIP_MEMORY_SCOPE_AGENT);
            while (__hip_atomic_load(rel, __ATOMIC_RELAXED,
                                     __HIP_MEMORY_SCOPE_AGENT) < phase)
                __builtin_amdgcn_s_sleep(2);
        }
    }
    __syncthreads();
    if (threadIdx.x < 64) __threadfence();   // acquire once per block (L1 per-CU)
    __syncthreads();
}

__global__ __launch_bounds__(256, 2) void cola_fused(
    const float* __restrict__ x, const float* __restrict__ adj,
    const float* __restrict__ Wih, const float* __restrict__ Whh,
    const float* __restrict__ bih, const float* __restrict__ bhh,
    const float* __restrict__ W1, const float* __restrict__ W2,
    const float* __restrict__ b1p, const float* __restrict__ Vp,
    const float* __restrict__ bvp, const float* __restrict__ Wb,
    const float* __restrict__ wbp, const float* __restrict__ conv_w,
    const float* __restrict__ conv_b, const float* __restrict__ convl_w,
    const float* __restrict__ convl_b, const float* __restrict__ gc1_w,
    const float* __restrict__ gc1_b, const float* __restrict__ gc2_w,
    const float* __restrict__ gc2_b, const float* __restrict__ out_w,
    const float* __restrict__ out_b, float* __restrict__ lh,
    float* __restrict__ e1, float* __restrict__ e2,
    float* __restrict__ nrmss, float* __restrict__ h1g,
    unsigned short* __restrict__ amxb, unsigned short* __restrict__ adjmixb,
    unsigned short* __restrict__ WbT, unsigned short* __restrict__ rgT,
    float* __restrict__ out, unsigned* cnt)
{
    __shared__ __align__(16) char smem[23552];
    const int blk = blockIdx.x;
    const int t = threadIdx.x;
    unsigned* flags = cnt;          // [512]
    unsigned* rel   = cnt + 512;

    // ================= Phase 0: RNN+e+conv+rg | WbT | nrmss=0 =============
    if (blk < 256) {
        int wid = t >> 6, lane = t & 63;
        int rowblk = blk * 32;
        int b = rowblk >> 9, mb = rowblk & 511;
        float* xs = (float*)smem;                               // [32][32]
        unsigned short* hs = (unsigned short*)(smem + 4096);    // [2][16][72]
        float* rrs = (float*)(smem + 8704);                     // [32][25]

        for (int u = t; u < 1024; u += 256) {
            int tt = u >> 5, c = u & 31;
            xs[tt * 32 + c] = x[(b * 32 + tt) * 512 + mb + c];
        }
        for (int u = t; u < 2304; u += 256) hs[u] = 0;
        __syncthreads();

        if (wid < 2) {
            // RNN (waves 0,1; 16 series each)
            int l15 = lane & 15, quad = lane >> 4;
            int row0 = rowblk + wid * 16;
            unsigned short* hw0 = hs + wid * 1152;

            bf16x8 afr[4][2];
#pragma unroll
            for (int mt = 0; mt < 4; ++mt)
#pragma unroll
                for (int hf = 0; hf < 2; ++hf) {
                    const float* src = Whh + (16 * mt + l15) * 64 + 32 * hf + quad * 8;
                    union { bf16x8 v; unsigned short u[8]; } tmp;
#pragma unroll
                    for (int j = 0; j < 8; ++j) tmp.u[j] = f2bf(src[j]);
                    afr[mt][hf] = tmp.v;
                }
            bf16x8 wfr[2][2][2];
#pragma unroll
            for (int e = 0; e < 2; ++e)
#pragma unroll
                for (int nt = 0; nt < 2; ++nt)
#pragma unroll
                    for (int kf = 0; kf < 2; ++kf) {
                        const float* Wsrc = (e ? W2 : W1);
                        const float* src = Wsrc + (16 * nt + l15) * 64 + 32 * kf + quad * 8;
                        union { bf16x8 v; unsigned short u[8]; } tmp;
#pragma unroll
                        for (int j = 0; j < 8; ++j) tmp.u[j] = f2bf(src[j]);
                        wfr[e][nt][kf] = tmp.v;
                    }
            float wihv[4][4], bsv[4][4];
#pragma unroll
            for (int mt = 0; mt < 4; ++mt)
#pragma unroll
                for (int r = 0; r < 4; ++r) {
                    int n = 16 * mt + quad * 4 + r;
                    wihv[mt][r] = Wih[n];
                    bsv[mt][r]  = bih[n] + bhh[n];
                }

            float th[4][4];
            for (int tstep = 0; tstep < 32; ++tstep) {
                bf16x8 b0 = *(bf16x8*)(hw0 + l15 * 72 + quad * 8);
                bf16x8 b1 = *(bf16x8*)(hw0 + l15 * 72 + 32 + quad * 8);
                float xt = xs[tstep * 32 + wid * 16 + l15];
                f32x4 acc[4];
#pragma unroll
                for (int mt = 0; mt < 4; ++mt) {
                    f32x4 z = {0.f, 0.f, 0.f, 0.f};
                    acc[mt] = MFMA16(afr[mt][0], b0, z, 0, 0, 0);
                    acc[mt] = MFMA16(afr[mt][1], b1, acc[mt], 0, 0, 0);
                }
#pragma unroll
                for (int mt = 0; mt < 4; ++mt) {
                    ushort4 hwv;
#pragma unroll
                    for (int r = 0; r < 4; ++r)
                        th[mt][r] = fast_tanh(acc[mt][r] + xt * wihv[mt][r] + bsv[mt][r]);
                    hwv.x = f2bf(th[mt][0]); hwv.y = f2bf(th[mt][1]);
                    hwv.z = f2bf(th[mt][2]); hwv.w = f2bf(th[mt][3]);
                    *(ushort4*)(hw0 + l15 * 72 + 16 * mt + quad * 4) = hwv;
                }
            }
#pragma unroll
            for (int mt = 0; mt < 4; ++mt)
                *(float4*)(lh + (row0 + l15) * 64 + 16 * mt + quad * 4) =
                    make_float4(th[mt][0], th[mt][1], th[mt][2], th[mt][3]);

            bf16x8 a0 = *(bf16x8*)(hw0 + l15 * 72 + quad * 8);
            bf16x8 a1 = *(bf16x8*)(hw0 + l15 * 72 + 32 + quad * 8);
#pragma unroll
            for (int e = 0; e < 2; ++e) {
                float* dst = e ? e2 : e1;
#pragma unroll
                for (int nt = 0; nt < 2; ++nt) {
                    f32x4 z = {0.f, 0.f, 0.f, 0.f};
                    f32x4 ee = MFMA16(a0, wfr[e][nt][0], z, 0, 0, 0);
                    ee = MFMA16(a1, wfr[e][nt][1], ee, 0, 0, 0);
#pragma unroll
                    for (int r = 0; r < 4; ++r)
                        dst[(row0 + quad * 4 + r) * 32 + 16 * nt + l15] = ee[r];
                }
            }
        } else {
            // conv + rg (waves 2,3; 16 rows each)
            int wid2 = wid - 2;
#pragma unroll
            for (int rep = 0; rep < 2; ++rep) {
                int task = rep * 64 + lane;            // 128 tasks = 16 rows x 8 k
                int rl = wid2 * 16 + (task >> 3);
                int k  = task & 7;
                float s = conv_b[k];
                for (int w = 0; w < 32; ++w) s += xs[w * 32 + rl] * conv_w[k * 32 + w];
                float l0 = convl_b[k], l1 = l0;
                for (int tt = 0; tt < 16; ++tt) {
                    float wv = convl_w[k * 16 + tt];
                    l0 += xs[(2 * tt) * 32 + rl] * wv;
                    l1 += xs[(2 * tt + 1) * 32 + rl] * wv;
                }
                rrs[rl * 25 + k * 3 + 0] = fmaxf(s, 0.f);
                rrs[rl * 25 + k * 3 + 1] = fmaxf(l0, 0.f);
                rrs[rl * 25 + k * 3 + 2] = fmaxf(l1, 0.f);
            }
            __builtin_amdgcn_wave_barrier();
            int rl = wid2 * 16 + (lane & 15);
            int nb = lane >> 4;
#pragma unroll
            for (int q = 0; q < 16; ++q) {
                int n = nb * 16 + q;
                float acc = 0.f;
#pragma unroll
                for (int c = 0; c < 24; ++c) acc += rrs[rl * 25 + c] * gc1_w[c * 64 + n];
                rgT[b * 32768 + n * 512 + mb + rl] = f2bf(acc);
            }
        }
    } else {
        // Wb transpose (256 blocks) + nrmss zero (first 32 of them)
        int bid = blk - 256;
        if (bid < 32) nrmss[bid * 256 + t] = 0.f;
        int nb = (bid & 15) * 32, kb = (bid >> 4) * 32;
        float* tile = (float*)smem;             // [32][33]
        for (int u = t; u < 1024; u += 256) {
            int r = u >> 5, c = u & 31;
            tile[r * 33 + c] = Wb[(kb + r) * 512 + nb + c];
        }
        __syncthreads();
        for (int u = t; u < 1024; u += 256) {
            int r = u >> 5, c = u & 31;
            WbT[(nb + r) * 512 + kb + c] = f2bf(tile[c * 33 + r]);
        }
    }
    gbar(flags, rel, 1u);

    // ================= Phase 1: amx, 2 tiles/block ========================
    {
        float (*e2s)[33] = (float (*)[33])smem;                 // 8448
        float (*e1s)[33] = (float (*)[33])(smem + 8448);        // 8448
        float* Vs        = (float*)(smem + 16896);              // 128
        float (*red)[68] = (float (*)[68])(smem + 17024);       // 4352
        const int ti = (t >> 4) * 4, tj = (t & 15) * 4;
        const float bv = bvp[0];
#pragma unroll 1
        for (int rep = 0; rep < 2; ++rep) {
            const int vt = blk * 2 + rep;
            const int bb = vt >> 6;
            const int i0 = ((vt >> 3) & 7) * 64;
            const int j0 = (vt & 7) * 64;
            __syncthreads();        // guard LDS overwrite vs prev rep reads
            for (int u = t; u < 2048; u += 256) {
                int r = u >> 5, c = u & 31;
                e2s[r][c] = e2[(bb * 512 + i0 + r) * 32 + c];
                e1s[r][c] = e1[(bb * 512 + j0 + r) * 32 + c] + b1p[c];
            }
            if (t < 32) Vs[t] = Vp[t];
            __syncthreads();
            float acc[4][4] = {};
#pragma unroll
            for (int h = 0; h < 32; ++h) {
                float vv = Vs[h];
                float xi[4], yj[4], Exi[4], Eyj[4];
#pragma unroll
                for (int p = 0; p < 4; ++p) { xi[p] = e2s[ti + p][h]; Exi[p] = __expf(xi[p]); }
#pragma unroll
                for (int q = 0; q < 4; ++q) { yj[q] = e1s[tj + q][h]; Eyj[q] = __expf(yj[q]); }
#pragma unroll
                for (int p = 0; p < 4; ++p)
#pragma unroll
                    for (int q = 0; q < 4; ++q) {
                        float v = xi[p] + yj[q];
                        float prod = Exi[p] * Eyj[q];
                        float el = v > 0.f ? v : prod - 1.f;  // exp(xi+yj)=Exi*Eyj
                        acc[p][q] += vv * el;
                    }
            }
            float ss[4] = {0.f, 0.f, 0.f, 0.f};
#pragma unroll
            for (int p = 0; p < 4; ++p) {
                float v0 = acc[p][0] + bv, v1 = acc[p][1] + bv;
                float v2 = acc[p][2] + bv, v3 = acc[p][3] + bv;
                ushort4 o;
                o.x = f2bf(v0); o.y = f2bf(v1); o.z = f2bf(v2); o.w = f2bf(v3);
                *(ushort4*)(amxb + (bb * 512 + i0 + ti + p) * 512 + j0 + tj) = o;
                ss[0] += v0 * v0; ss[1] += v1 * v1; ss[2] += v2 * v2; ss[3] += v3 * v3;
            }
#pragma unroll
            for (int q = 0; q < 4; ++q) red[t >> 4][tj + q] = ss[q];
            __syncthreads();
            if (t < 64) {
                float s = 0.f;
#pragma unroll
                for (int g = 0; g < 16; ++g) s += red[g][t];
                atomicAdd(&nrmss[bb * 512 + j0 + t], s);
            }
        }
    }
    gbar(flags, rel, 2u);

    // ================= Phase 2: gemm_adjmix, 2 tiles/block ================
    {
        short* As = (short*)smem;               // 9216
        short* Bs = (short*)(smem + 9216);      // 9216
        float* rn = (float*)(smem + 18432);     // 2048
        const int w = t >> 6, lane = t & 63;
        const int l15 = lane & 15, quad = lane >> 4;
        const float wb = wbp[0];
#pragma unroll 1
        for (int rep = 0; rep < 2; ++rep) {
            const int vt = blk * 2 + rep;
            const int bb = vt >> 6;
            const int i0 = ((vt >> 3) & 7) * 64;
            const int j0 = (vt & 7) * 64;
            // idempotent across reps (same bb); ordered vs prev-rep reads by
            // the k-loop's barriers
            for (int u = t; u < 512; u += 256)
                rn[u] = 1.f / fmaxf(sqrtf(nrmss[bb * 512 + u]), 1e-12f);
            const unsigned short* Ag = amxb + bb * 262144;
            f32x4 acc[4] = {};
            for (int kk = 1; kk <= 8; ++kk) {
                int k0 = (j0 + 64 * kk) & 511;      // last iter: k0 == j0
                __syncthreads();
#pragma unroll
                for (int u0 = 0; u0 < 2; ++u0) {
                    int u = t + u0 * 256;
                    int i = u >> 3, o = u & 7;
                    *(int4*)(Bs + i * 72 + o * 8) =
                        *(const int4*)(WbT + (j0 + i) * 512 + k0 + o * 8);
                    union { int4 v; unsigned short us[8]; } ur;
                    ur.v = *(const int4*)(Ag + (i0 + i) * 512 + k0 + o * 8);
                    union { int4 v; unsigned short us[8]; } ow2;
#pragma unroll
                    for (int c = 0; c < 8; ++c)
                        ow2.us[c] = f2bf(bf2f(ur.us[c]) * rn[k0 + o * 8 + c]);
                    *(int4*)(As + i * 72 + o * 8) = ow2.v;
                }
                __syncthreads();
                bf16x8 a0 = *(bf16x8*)(As + (16 * w + l15) * 72 + quad * 8);
                bf16x8 a1 = *(bf16x8*)(As + (16 * w + l15) * 72 + 32 + quad * 8);
#pragma unroll
                for (int nt = 0; nt < 4; ++nt) {
                    bf16x8 b0 = *(bf16x8*)(Bs + (16 * nt + l15) * 72 + quad * 8);
                    bf16x8 b1 = *(bf16x8*)(Bs + (16 * nt + l15) * 72 + 32 + quad * 8);
                    acc[nt] = MFMA16(a0, b0, acc[nt], 0, 0, 0);
                    acc[nt] = MFMA16(a1, b1, acc[nt], 0, 0, 0);
                }
            }
            // As now holds scaled amx(i0:64, j0:64)
#pragma unroll
            for (int nt = 0; nt < 4; ++nt)
#pragma unroll
            for (int r = 0; r < 4; ++r) {
                int il = 16 * w + quad * 4 + r;
                int jl = 16 * nt + l15;
                int i = i0 + il, j = j0 + jl;
                float s  = acc[nt][r] + wb;
                float cv = 1.f / (1.f + __expf(-s));
                float am = bf2f((unsigned short)As[il * 72 + jl]);
                float ad = adj[i * 512 + j];
                adjmixb[(bb * 512 + i) * 512 + j] = f2bf(ad * cv + am * (1.f - cv));
            }
            // next rep's first k-iter __syncthreads orders As overwrite
        }
    }
    gbar(flags, rel, 3u);

    // ================= Phase 3: gemm_h1 + h1g (blocks<256) ================
    if (blk < 256) {
        short* As = (short*)smem;                           // 4608
        short* Bs = (short*)(smem + 4608);                  // 9216
        float (*h1s)[72] = (float (*)[72])(smem + 13824);   // 9216 -> 23040
        const int bb = blk >> 4;
        const int i0 = (blk & 15) * 32;
        const int w = t >> 6, lane = t & 63;
        const int l15 = lane & 15, quad = lane >> 4;
        const int rt = w & 1, ntb = (w >> 1) * 2;
        const unsigned short* Ag = adjmixb + bb * 262144;
        const unsigned short* Bg = rgT + bb * 32768;
        f32x4 acc[2] = {};
        for (int k0 = 0; k0 < 512; k0 += 64) {
            __syncthreads();
            {
                int i = t >> 3, o = t & 7;
                *(int4*)(As + i * 72 + o * 8) =
                    *(const int4*)(Ag + (i0 + i) * 512 + k0 + o * 8);
            }
#pragma unroll
            for (int u0 = 0; u0 < 2; ++u0) {
                int u = t + u0 * 256;
                int i = u >> 3, o = u & 7;
                *(int4*)(Bs + i * 72 + o * 8) =
                    *(const int4*)(Bg + i * 512 + k0 + o * 8);
            }
            __syncthreads();
            bf16x8 a0 = *(bf16x8*)(As + (16 * rt + l15) * 72 + quad * 8);
            bf16x8 a1 = *(bf16x8*)(As + (16 * rt + l15) * 72 + 32 + quad * 8);
#pragma unroll
            for (int q = 0; q < 2; ++q) {
                int nt = ntb + q;
                bf16x8 b0 = *(bf16x8*)(Bs + (16 * nt + l15) * 72 + quad * 8);
                bf16x8 b1 = *(bf16x8*)(Bs + (16 * nt + l15) * 72 + 32 + quad * 8);
                acc[q] = MFMA16(a0, b0, acc[q], 0, 0, 0);
                acc[q] = MFMA16(a1, b1, acc[q], 0, 0, 0);
            }
        }
#pragma unroll
        for (int q = 0; q < 2; ++q)
#pragma unroll
        for (int r = 0; r < 4; ++r) {
            int il = 16 * rt + quad * 4 + r;
            int j = 16 * (ntb + q) + l15;
            h1s[il][j] = fmaxf(acc[q][r] + gc1_b[j], 0.f);
        }
        __syncthreads();
        for (int u = t; u < 320; u += 256) {
            int row = u / 10, ns = u - row * 10;
            float a2 = 0.f;
#pragma unroll
            for (int j = 0; j < 64; ++j) a2 += h1s[row][j] * gc2_w[j * 10 + ns];
            h1g[(bb * 512 + i0 + row) * 10 + ns] = a2;
        }
    }
    gbar(flags, rel, 4u);

    // ================= Phase 4: ospout (16 rows/block) =====================
    {
        float (*Bsm)[512] = (float (*)[512])smem;           // 20480
        float (*ow)[80]   = (float (*)[80])(smem + 20480);  // 2560
        float* ob  = (float*)(smem + 23040);                // 32
        float* g2b = (float*)(smem + 23072);                // 40
        const int r0 = blk * 16;
        const int bb = r0 >> 9;
        const int wid = t >> 6, lane = t & 63;
        for (int u = t; u < 5120; u += 256) {
            int k = u / 10, ns = u - k * 10;
            Bsm[ns][k] = h1g[bb * 5120 + u];
        }
        if (t < 8)  ob[t]  = out_b[t];
        if (t < 10) g2b[t] = gc2_b[t];
        for (int u = t; u < 592; u += 256) {
            int hh = u / 74, c = u - hh * 74;
            ow[hh][c] = out_w[u];
        }
        __syncthreads();
#pragma unroll
        for (int half = 0; half < 4; ++half) {
            int row = r0 + half * 4 + wid, m = row & 511;
            const unsigned short* Ar = adjmixb + row * 512;
            float a[8];
#pragma unroll
            for (int q = 0; q < 8; ++q) a[q] = bf2f(Ar[lane + 64 * q]);
            float os[10];
#pragma unroll
            for (int ns = 0; ns < 10; ++ns) {
                float s = 0.f;
#pragma unroll
                for (int q = 0; q < 8; ++q) s += a[q] * Bsm[ns][lane + 64 * q];
#pragma unroll
                for (int off = 32; off; off >>= 1) s += __shfl_xor(s, off);
                os[ns] = fmaxf(s + g2b[ns], 0.f);
            }
            float lv = lh[row * 64 + lane];
#pragma unroll
            for (int hh = 0; hh < 8; ++hh) {
                float t1 = lv * ow[hh][10 + lane];
#pragma unroll
                for (int off = 32; off; off >>= 1) t1 += __shfl_xor(t1, off);
                if (lane == hh) {
                    float acc = ob[hh] + t1;
#pragma unroll
                    for (int ns = 0; ns < 10; ++ns) acc += os[ns] * ow[hh][ns];
                    out[bb * 4096 + hh * 512 + m] = acc;
                }
            }
        }
    }
}

// ---------------- launch ---------------------------------------------------
extern "C" void kernel_launch(void* const* d_in, const int* in_sizes, int n_in,
                              void* d_out, int out_size, void* d_ws, size_t ws_size,
                              hipStream_t stream)
{
    const float* x       = (const float*)d_in[0];
    const float* adj     = (const float*)d_in[1];
    const float* Wih     = (const float*)d_in[2];
    const float* Whh     = (const float*)d_in[3];
    const float* bih     = (const float*)d_in[4];
    const float* bhh     = (const float*)d_in[5];
    const float* W1      = (const float*)d_in[6];
    const float* W2      = (const float*)d_in[7];
    const float* b1      = (const float*)d_in[8];
    const float* V       = (const float*)d_in[9];
    const float* bv      = (const float*)d_in[10];
    const float* Wb      = (const float*)d_in[11];
    const float* wb      = (const float*)d_in[12];
    const float* conv_w  = (const float*)d_in[13];
    const float* conv_b  = (const float*)d_in[14];
    const float* convl_w = (const float*)d_in[15];
    const float* convl_b = (const float*)d_in[16];
    const float* gc1_w   = (const float*)d_in[17];
    const float* gc1_b   = (const float*)d_in[18];
    const float* gc2_w   = (const float*)d_in[19];
    const float* gc2_b   = (const float*)d_in[20];
    const float* out_w   = (const float*)d_in[21];
    const float* out_b   = (const float*)d_in[22];

    float* ws    = (float*)d_ws;
    float* lh    = ws;                  // 524288 floats
    float* e1    = lh + 524288;         // 262144
    float* e2    = e1 + 262144;         // 262144
    float* nrmss = e2 + 262144;         // 8192
    float* h1g   = nrmss + 8192;        // 81920
    unsigned short* amxb    = (unsigned short*)(h1g + 81920);  // 4194304 shorts
    unsigned short* adjmixb = amxb + 4194304;                  // 4194304
    unsigned short* WbT     = adjmixb + 4194304;               // 262144
    unsigned short* rgT     = WbT + 262144;                    // 524288
    unsigned* cnt = (unsigned*)(rgT + 524288);                 // flags[512]+rel
    float* outp = (float*)d_out;

    hipMemsetAsync(cnt, 0, 4096, stream);
    cola_fused<<<512, 256, 0, stream>>>(
        x, adj, Wih, Whh, bih, bhh, W1, W2, b1, V, bv, Wb, wb,
        conv_w, conv_b, convl_w, convl_b, gc1_w, gc1_b, gc2_w, gc2_b,
        out_w, out_b, lh, e1, e2, nrmss, h1g, amxb, adjmixb, WbT, rgT,
        outp, cnt);
}

// Round 5
// 220.286 us; speedup vs baseline: 3.1433x; 1.4634x over previous
//
#include <hip/hip_runtime.h>

// dims: B=16 W=32 M=512 NH=64 HALF=32 K=8 H=8 LK=16 LOUT=2 NSP=10 GCIN=24
// rows = B*M = 8192. Reference dtypes fp32; bf16 internally for MFMA.
// 4 dispatches (was 5): fused1(rnn+e+conv+rg | wbt | zero), amx,
// gemm_adjmix_h1 (K3+K4 merged: block owns 32-row panel -> adjmix rows
// then h1 from OWN rows; K3->K4 boundary was a block-local dependency),
// ospout(+final proj).
// Persistent-kernel experiments R1-R4: software global barriers cost
// ~45us each (per-block agent-fence = per-block L2 buffer_inv, 64/XCD
// serialized) -- structurally worse than HW dispatch boundaries. Reverted.

typedef __attribute__((ext_vector_type(8))) short bf16x8;
typedef __attribute__((ext_vector_type(4))) float f32x4;
#define MFMA16 __builtin_amdgcn_mfma_f32_16x16x32_bf16

__device__ __forceinline__ unsigned short f2bf(float f) {
    unsigned u = __float_as_uint(f);
    u += 0x7fff + ((u >> 16) & 1);          // RNE
    return (unsigned short)(u >> 16);
}
__device__ __forceinline__ float bf2f(unsigned short h) {
    return __uint_as_float(((unsigned)h) << 16);
}
__device__ __forceinline__ float fast_tanh(float x) {
    float e = __expf(2.f * x);
    return 1.f - 2.f / (e + 1.f);
}

// ---------------- K1: fused1 ----------------------------------------------
// blocks [0,256): 32 series each. Waves 0-1: RNN via MFMA + e1/e2 epilogue.
//                 Waves 2-3: conv+rg for the same 32 rows.
// blocks [256,512): Wb transpose->bf16
// blocks [512,544): zero nrmss
__global__ __launch_bounds__(256) void fused1_kernel(
    const float* __restrict__ x, const float* __restrict__ Wih,
    const float* __restrict__ Whh, const float* __restrict__ bih,
    const float* __restrict__ bhh, const float* __restrict__ W1,
    const float* __restrict__ W2, float* __restrict__ lh,
    float* __restrict__ e1, float* __restrict__ e2,
    const float* __restrict__ conv_w, const float* __restrict__ conv_b,
    const float* __restrict__ convl_w, const float* __restrict__ convl_b,
    const float* __restrict__ gc1_w, unsigned short* __restrict__ rgT,
    const float* __restrict__ Wb, unsigned short* __restrict__ WbT,
    float* __restrict__ nrmss)
{
    __shared__ __align__(16) char smem[12160];
    int blk = blockIdx.x, t = threadIdx.x;

    if (blk < 256) {
        int wid = t >> 6, lane = t & 63;
        int rowblk = blk * 32;
        int b = rowblk >> 9, mb = rowblk & 511;
        float* xs = (float*)smem;                               // [32][32]
        unsigned short* hs = (unsigned short*)(smem + 4096);    // [2][16][72]
        float* rrs = (float*)(smem + 8704);                     // [32][25]

        for (int u = t; u < 1024; u += 256) {
            int tt = u >> 5, c = u & 31;
            xs[tt * 32 + c] = x[(b * 32 + tt) * 512 + mb + c];
        }
        for (int u = t; u < 2304; u += 256) hs[u] = 0;
        __syncthreads();

        if (wid < 2) {
            // RNN (waves 0,1; 16 series each)
            int l15 = lane & 15, quad = lane >> 4;
            int row0 = rowblk + wid * 16;
            unsigned short* hw0 = hs + wid * 1152;

            bf16x8 afr[4][2];
#pragma unroll
            for (int mt = 0; mt < 4; ++mt)
#pragma unroll
                for (int hf = 0; hf < 2; ++hf) {
                    const float* src = Whh + (16 * mt + l15) * 64 + 32 * hf + quad * 8;
                    union { bf16x8 v; unsigned short u[8]; } tmp;
#pragma unroll
                    for (int j = 0; j < 8; ++j) tmp.u[j] = f2bf(src[j]);
                    afr[mt][hf] = tmp.v;
                }
            bf16x8 wfr[2][2][2];
#pragma unroll
            for (int e = 0; e < 2; ++e)
#pragma unroll
                for (int nt = 0; nt < 2; ++nt)
#pragma unroll
                    for (int kf = 0; kf < 2; ++kf) {
                        const float* Wsrc = (e ? W2 : W1);
                        const float* src = Wsrc + (16 * nt + l15) * 64 + 32 * kf + quad * 8;
                        union { bf16x8 v; unsigned short u[8]; } tmp;
#pragma unroll
                        for (int j = 0; j < 8; ++j) tmp.u[j] = f2bf(src[j]);
                        wfr[e][nt][kf] = tmp.v;
                    }
            float wihv[4][4], bsv[4][4];
#pragma unroll
            for (int mt = 0; mt < 4; ++mt)
#pragma unroll
                for (int r = 0; r < 4; ++r) {
                    int n = 16 * mt + quad * 4 + r;
                    wihv[mt][r] = Wih[n];
                    bsv[mt][r]  = bih[n] + bhh[n];
                }

            float th[4][4];
            for (int tstep = 0; tstep < 32; ++tstep) {
                bf16x8 b0 = *(bf16x8*)(hw0 + l15 * 72 + quad * 8);
                bf16x8 b1 = *(bf16x8*)(hw0 + l15 * 72 + 32 + quad * 8);
                float xt = xs[tstep * 32 + wid * 16 + l15];
                f32x4 acc[4];
#pragma unroll
                for (int mt = 0; mt < 4; ++mt) {
                    f32x4 z = {0.f, 0.f, 0.f, 0.f};
                    acc[mt] = MFMA16(afr[mt][0], b0, z, 0, 0, 0);
                    acc[mt] = MFMA16(afr[mt][1], b1, acc[mt], 0, 0, 0);
                }
#pragma unroll
                for (int mt = 0; mt < 4; ++mt) {
                    ushort4 hwv;
#pragma unroll
                    for (int r = 0; r < 4; ++r)
                        th[mt][r] = fast_tanh(acc[mt][r] + xt * wihv[mt][r] + bsv[mt][r]);
                    hwv.x = f2bf(th[mt][0]); hwv.y = f2bf(th[mt][1]);
                    hwv.z = f2bf(th[mt][2]); hwv.w = f2bf(th[mt][3]);
                    *(ushort4*)(hw0 + l15 * 72 + 16 * mt + quad * 4) = hwv;
                }
            }
#pragma unroll
            for (int mt = 0; mt < 4; ++mt)
                *(float4*)(lh + (row0 + l15) * 64 + 16 * mt + quad * 4) =
                    make_float4(th[mt][0], th[mt][1], th[mt][2], th[mt][3]);

            bf16x8 a0 = *(bf16x8*)(hw0 + l15 * 72 + quad * 8);
            bf16x8 a1 = *(bf16x8*)(hw0 + l15 * 72 + 32 + quad * 8);
#pragma unroll
            for (int e = 0; e < 2; ++e) {
                float* dst = e ? e2 : e1;
#pragma unroll
                for (int nt = 0; nt < 2; ++nt) {
                    f32x4 z = {0.f, 0.f, 0.f, 0.f};
                    f32x4 ee = MFMA16(a0, wfr[e][nt][0], z, 0, 0, 0);
                    ee = MFMA16(a1, wfr[e][nt][1], ee, 0, 0, 0);
#pragma unroll
                    for (int r = 0; r < 4; ++r)
                        dst[(row0 + quad * 4 + r) * 32 + 16 * nt + l15] = ee[r];
                }
            }
        } else {
            // conv + rg (waves 2,3; 16 rows each)
            int wid2 = wid - 2;
#pragma unroll
            for (int rep = 0; rep < 2; ++rep) {
                int task = rep * 64 + lane;            // 128 tasks = 16 rows x 8 k
                int rl = wid2 * 16 + (task >> 3);
                int k  = task & 7;
                float s = conv_b[k];
                for (int w = 0; w < 32; ++w) s += xs[w * 32 + rl] * conv_w[k * 32 + w];
                float l0 = convl_b[k], l1 = l0;
                for (int tt = 0; tt < 16; ++tt) {
                    float wv = convl_w[k * 16 + tt];
                    l0 += xs[(2 * tt) * 32 + rl] * wv;
                    l1 += xs[(2 * tt + 1) * 32 + rl] * wv;
                }
                rrs[rl * 25 + k * 3 + 0] = fmaxf(s, 0.f);
                rrs[rl * 25 + k * 3 + 1] = fmaxf(l0, 0.f);
                rrs[rl * 25 + k * 3 + 2] = fmaxf(l1, 0.f);
            }
            // intra-wave LDS RAW: in-order DS per wave; no cross-wave dep
            __builtin_amdgcn_wave_barrier();
            int rl = wid2 * 16 + (lane & 15);
            int nb = lane >> 4;
#pragma unroll
            for (int q = 0; q < 16; ++q) {
                int n = nb * 16 + q;
                float acc = 0.f;
#pragma unroll
                for (int c = 0; c < 24; ++c) acc += rrs[rl * 25 + c] * gc1_w[c * 64 + n];
                rgT[b * 32768 + n * 512 + mb + rl] = f2bf(acc);
            }
        }
    } else if (blk < 512) {
        // ---------------- Wb transpose ----------------
        int bid = blk - 256;
        int nb = (bid & 15) * 32, kb = (bid >> 4) * 32;
        float* tile = (float*)smem;             // [32][33]
        for (int u = t; u < 1024; u += 256) {
            int r = u >> 5, c = u & 31;
            tile[r * 33 + c] = Wb[(kb + r) * 512 + nb + c];
        }
        __syncthreads();
        for (int u = t; u < 1024; u += 256) {
            int r = u >> 5, c = u & 31;
            WbT[(nb + r) * 512 + kb + c] = f2bf(tile[c * 33 + r]);
        }
    } else {
        nrmss[(blk - 512) * 256 + t] = 0.f;
    }
}

// ---------------- K2: a_mx 4x4/thread, factorized exp, fused sumsq --------
__global__ __launch_bounds__(256) void amx_kernel(
    const float* __restrict__ e1, const float* __restrict__ e2,
    const float* __restrict__ b1p, const float* __restrict__ Vp,
    const float* __restrict__ bvp, unsigned short* __restrict__ amxb,
    float* __restrict__ nrmss)
{
    int bb = blockIdx.z;
    int i0 = blockIdx.y * 64, j0 = blockIdx.x * 64;
    __shared__ float e2s[64][33], e1s[64][33];
    __shared__ float Vs[32];
    __shared__ float red[16][68];
    int t = threadIdx.x;
    for (int u = t; u < 2048; u += 256) {
        int r = u >> 5, c = u & 31;
        e2s[r][c] = e2[(bb * 512 + i0 + r) * 32 + c];
        e1s[r][c] = e1[(bb * 512 + j0 + r) * 32 + c] + b1p[c];
    }
    if (t < 32) Vs[t] = Vp[t];
    __syncthreads();
    int ti = (t >> 4) * 4, tj = (t & 15) * 4;
    float acc[4][4] = {};
#pragma unroll
    for (int h = 0; h < 32; ++h) {
        float vv = Vs[h];
        float xi[4], yj[4], Exi[4], Eyj[4];
#pragma unroll
        for (int p = 0; p < 4; ++p) { xi[p] = e2s[ti + p][h]; Exi[p] = __expf(xi[p]); }
#pragma unroll
        for (int q = 0; q < 4; ++q) { yj[q] = e1s[tj + q][h]; Eyj[q] = __expf(yj[q]); }
#pragma unroll
        for (int p = 0; p < 4; ++p)
#pragma unroll
            for (int q = 0; q < 4; ++q) {
                float v = xi[p] + yj[q];
                float prod = Exi[p] * Eyj[q];
                float el = v > 0.f ? v : prod - 1.f;  // exp(xi+yj)=Exi*Eyj
                acc[p][q] += vv * el;
            }
    }
    float bv = bvp[0];
    float ss[4] = {0.f, 0.f, 0.f, 0.f};
#pragma unroll
    for (int p = 0; p < 4; ++p) {
        float v0 = acc[p][0] + bv, v1 = acc[p][1] + bv;
        float v2 = acc[p][2] + bv, v3 = acc[p][3] + bv;
        ushort4 o;
        o.x = f2bf(v0); o.y = f2bf(v1); o.z = f2bf(v2); o.w = f2bf(v3);
        *(ushort4*)(amxb + (bb * 512 + i0 + ti + p) * 512 + j0 + tj) = o;
        ss[0] += v0 * v0; ss[1] += v1 * v1; ss[2] += v2 * v2; ss[3] += v3 * v3;
    }
#pragma unroll
    for (int q = 0; q < 4; ++q) red[t >> 4][tj + q] = ss[q];
    __syncthreads();
    if (t < 64) {
        float s = 0.f;
#pragma unroll
        for (int g = 0; g < 16; ++g) s += red[g][t];
        atomicAdd(&nrmss[bb * 512 + j0 + t], s);
    }
}

// ---------------- K3: gemm_adjmix + gemm_h1 merged ------------------------
// Block owns a 32-row panel (bb, i0:i0+32). Part A: for each of 8 j-tiles,
// wrap-ordered k-loop (last A-tile == j-tile) -> adjmix rows to global.
// Part B: h1 = relu(adjmix_own_rows @ rg + b) + h1g, A-reads are this
// block's own just-written rows (L1/L2-hot, no cross-block dep).
// 1 block/CU during this kernel -> register prefetch in both k-loops to
// hide load latency that co-resident blocks previously hid.
__global__ __launch_bounds__(256) void gemm_adjmix_h1(
    const unsigned short* __restrict__ amxb, const unsigned short* __restrict__ WbT,
    const float* __restrict__ wbp, const float* __restrict__ adj,
    const float* __restrict__ nrmss, unsigned short* __restrict__ adjmixb,
    const unsigned short* __restrict__ rgT, const float* __restrict__ gc1_b,
    const float* __restrict__ gc2_w, float* __restrict__ h1g)
{
    const int bb = blockIdx.y;
    const int i0 = blockIdx.x * 32;
    __shared__ __align__(16) char smem[23552];
    short* As = (short*)smem;                           // [32][72]
    short* Bs = (short*)(smem + 4608);                  // [64][72]
    float* rn = (float*)(smem + 13824);                 // [512] (dies before h1s)
    float (*h1s)[72] = (float (*)[72])(smem + 13824);   // [32][72] (part B)

    const int t = threadIdx.x, w = t >> 6, lane = t & 63;
    const int l15 = lane & 15, quad = lane >> 4;
    const int rh = w & 1, ch = w >> 1;                  // row-half, col-half
    const int si = t >> 3, so = t & 7;                  // stage coords

    for (int u = t; u < 512; u += 256)
        rn[u] = 1.f / fmaxf(sqrtf(nrmss[bb * 512 + u]), 1e-12f);
    const unsigned short* Ag = amxb + bb * 262144;
    const float wb = wbp[0];

    // ---- Part A: adjmix rows, 8 j-tiles x 8 k-tiles, reg-prefetched ------
    int4 pa, pb0, pb1;
    {   // prologue prefetch: (j0=0, kk=0) -> k0 = 64
        pa  = *(const int4*)(Ag + (i0 + si) * 512 + 64 + so * 8);
        pb0 = *(const int4*)(WbT + si * 512 + 64 + so * 8);
        pb1 = *(const int4*)(WbT + (32 + si) * 512 + 64 + so * 8);
    }
    f32x4 acc[2];
    const f32x4 zz = {0.f, 0.f, 0.f, 0.f};
    for (int it = 0; it < 64; ++it) {
        const int j0 = it >> 3, kk = it & 7;
        const int k0 = (j0 * 64 + 64 * (kk + 1)) & 511;   // kk==7 -> k0==j0*64
        __syncthreads();
        {   // write prefetched tile; scale A by rn
            union { int4 v; unsigned short us[8]; } ur; ur.v = pa;
            union { int4 v; unsigned short us[8]; } ow2;
#pragma unroll
            for (int c = 0; c < 8; ++c)
                ow2.us[c] = f2bf(bf2f(ur.us[c]) * rn[k0 + so * 8 + c]);
            *(int4*)(As + si * 72 + so * 8) = ow2.v;
            *(int4*)(Bs + si * 72 + so * 8) = pb0;
            *(int4*)(Bs + (32 + si) * 72 + so * 8) = pb1;
        }
        if (it < 63) {      // prefetch next tile (overlaps barrier+MFMA)
            const int itn = it + 1, j0n = itn >> 3, kkn = itn & 7;
            const int k0n = (j0n * 64 + 64 * (kkn + 1)) & 511;
            pa  = *(const int4*)(Ag + (i0 + si) * 512 + k0n + so * 8);
            pb0 = *(const int4*)(WbT + (j0n * 64 + si) * 512 + k0n + so * 8);
            pb1 = *(const int4*)(WbT + (j0n * 64 + 32 + si) * 512 + k0n + so * 8);
        }
        __syncthreads();
        if (kk == 0) { acc[0] = zz; acc[1] = zz; }
        bf16x8 a0 = *(bf16x8*)(As + (16 * rh + l15) * 72 + quad * 8);
        bf16x8 a1 = *(bf16x8*)(As + (16 * rh + l15) * 72 + 32 + quad * 8);
#pragma unroll
        for (int q = 0; q < 2; ++q) {
            int nt = ch * 2 + q;
            bf16x8 b0 = *(bf16x8*)(Bs + (16 * nt + l15) * 72 + quad * 8);
            bf16x8 b1 = *(bf16x8*)(Bs + (16 * nt + l15) * 72 + 32 + quad * 8);
            acc[q] = MFMA16(a0, b0, acc[q], 0, 0, 0);
            acc[q] = MFMA16(a1, b1, acc[q], 0, 0, 0);
        }
        if (kk == 7) {
            // As holds scaled amx(i0:+32, j0*64:+64)
#pragma unroll
            for (int q = 0; q < 2; ++q)
#pragma unroll
            for (int r = 0; r < 4; ++r) {
                int il = 16 * rh + quad * 4 + r;
                int jl = 16 * (ch * 2 + q) + l15;
                int i = i0 + il, j = j0 * 64 + jl;
                float s  = acc[q][r] + wb;
                float cv = 1.f / (1.f + __expf(-s));
                float am = bf2f((unsigned short)As[il * 72 + jl]);
                float ad = adj[i * 512 + j];
                adjmixb[(bb * 512 + i) * 512 + j] = f2bf(ad * cv + am * (1.f - cv));
            }
        }
    }

    // ---- Part B: h1 from own adjmix rows + h1g ---------------------------
    const unsigned short* Ag2 = adjmixb + bb * 262144;
    const unsigned short* Bg2 = rgT + bb * 32768;
    const int rt = w & 1, ntb = (w >> 1) * 2;
    f32x4 acc2[2] = {};
    int4 qa, qb0, qb1;
    {   // prologue prefetch k0=0 (j0=0 tile: written at it=7, long drained)
        qa  = *(const int4*)(Ag2 + (i0 + si) * 512 + so * 8);
        qb0 = *(const int4*)(Bg2 + si * 512 + so * 8);
        qb1 = *(const int4*)(Bg2 + (32 + si) * 512 + so * 8);
    }
    for (int kt = 0; kt < 8; ++kt) {
        __syncthreads();
        *(int4*)(As + si * 72 + so * 8) = qa;
        *(int4*)(Bs + si * 72 + so * 8) = qb0;
        *(int4*)(Bs + (32 + si) * 72 + so * 8) = qb1;
        if (kt < 7) {
            const int k0n = (kt + 1) * 64;
            qa  = *(const int4*)(Ag2 + (i0 + si) * 512 + k0n + so * 8);
            qb0 = *(const int4*)(Bg2 + si * 512 + k0n + so * 8);
            qb1 = *(const int4*)(Bg2 + (32 + si) * 512 + k0n + so * 8);
        }
        __syncthreads();
        bf16x8 a0 = *(bf16x8*)(As + (16 * rt + l15) * 72 + quad * 8);
        bf16x8 a1 = *(bf16x8*)(As + (16 * rt + l15) * 72 + 32 + quad * 8);
#pragma unroll
        for (int q = 0; q < 2; ++q) {
            int nt = ntb + q;
            bf16x8 b0 = *(bf16x8*)(Bs + (16 * nt + l15) * 72 + quad * 8);
            bf16x8 b1 = *(bf16x8*)(Bs + (16 * nt + l15) * 72 + 32 + quad * 8);
            acc2[q] = MFMA16(a0, b0, acc2[q], 0, 0, 0);
            acc2[q] = MFMA16(a1, b1, acc2[q], 0, 0, 0);
        }
    }
#pragma unroll
    for (int q = 0; q < 2; ++q)
#pragma unroll
    for (int r = 0; r < 4; ++r) {
        int il = 16 * rt + quad * 4 + r;
        int j = 16 * (ntb + q) + l15;
        h1s[il][j] = fmaxf(acc2[q][r] + gc1_b[j], 0.f);
    }
    __syncthreads();
    for (int u = t; u < 320; u += 256) {
        int row = u / 10, ns = u - row * 10;
        float a2 = 0.f;
#pragma unroll
        for (int j = 0; j < 64; ++j) a2 += h1s[row][j] * gc2_w[j * 10 + ns];
        h1g[(bb * 512 + i0 + row) * 10 + ns] = a2;
    }
}

// ---------------- K4: ospout, 16 rows/block -------------------------------
__global__ __launch_bounds__(256) void ospout_kernel(
    const unsigned short* __restrict__ adjmix, const float* __restrict__ h1g,
    const float* __restrict__ gc2_b, const float* __restrict__ lh,
    const float* __restrict__ out_w, const float* __restrict__ out_b,
    float* __restrict__ out)
{
    int r0 = blockIdx.x * 16;
    int bb = r0 >> 9;
    int wid = threadIdx.x >> 6, lane = threadIdx.x & 63;
    __shared__ float Bsm[10][512];
    __shared__ float ow[8][80];
    __shared__ float ob[8], g2b[10];
    for (int u = threadIdx.x; u < 5120; u += 256) {
        int k = u / 10, ns = u - k * 10;
        Bsm[ns][k] = h1g[bb * 5120 + u];
    }
    if (threadIdx.x < 8)  ob[threadIdx.x]  = out_b[threadIdx.x];
    if (threadIdx.x < 10) g2b[threadIdx.x] = gc2_b[threadIdx.x];
    for (int u = threadIdx.x; u < 592; u += 256) {
        int hh = u / 74, c = u - hh * 74;
        ow[hh][c] = out_w[u];
    }
    __syncthreads();
#pragma unroll
    for (int half = 0; half < 4; ++half) {
        int row = r0 + half * 4 + wid, m = row & 511;
        const unsigned short* Ar = adjmix + row * 512;
        float a[8];
#pragma unroll
        for (int q = 0; q < 8; ++q) a[q] = bf2f(Ar[lane + 64 * q]);
        float os[10];
#pragma unroll
        for (int ns = 0; ns < 10; ++ns) {
            float s = 0.f;
#pragma unroll
            for (int q = 0; q < 8; ++q) s += a[q] * Bsm[ns][lane + 64 * q];
#pragma unroll
            for (int off = 32; off; off >>= 1) s += __shfl_xor(s, off);
            os[ns] = fmaxf(s + g2b[ns], 0.f);
        }
        float lv = lh[row * 64 + lane];
#pragma unroll
        for (int hh = 0; hh < 8; ++hh) {
            float t1 = lv * ow[hh][10 + lane];
#pragma unroll
            for (int off = 32; off; off >>= 1) t1 += __shfl_xor(t1, off);
            if (lane == hh) {
                float acc = ob[hh] + t1;
#pragma unroll
                for (int ns = 0; ns < 10; ++ns) acc += os[ns] * ow[hh][ns];
                out[bb * 4096 + hh * 512 + m] = acc;
            }
        }
    }
}

// ---------------- launch ---------------------------------------------------
extern "C" void kernel_launch(void* const* d_in, const int* in_sizes, int n_in,
                              void* d_out, int out_size, void* d_ws, size_t ws_size,
                              hipStream_t stream)
{
    const float* x       = (const float*)d_in[0];
    const float* adj     = (const float*)d_in[1];
    const float* Wih     = (const float*)d_in[2];
    const float* Whh     = (const float*)d_in[3];
    const float* bih     = (const float*)d_in[4];
    const float* bhh     = (const float*)d_in[5];
    const float* W1      = (const float*)d_in[6];
    const float* W2      = (const float*)d_in[7];
    const float* b1      = (const float*)d_in[8];
    const float* V       = (const float*)d_in[9];
    const float* bv      = (const float*)d_in[10];
    const float* Wb      = (const float*)d_in[11];
    const float* wb      = (const float*)d_in[12];
    const float* conv_w  = (const float*)d_in[13];
    const float* conv_b  = (const float*)d_in[14];
    const float* convl_w = (const float*)d_in[15];
    const float* convl_b = (const float*)d_in[16];
    const float* gc1_w   = (const float*)d_in[17];
    const float* gc1_b   = (const float*)d_in[18];
    const float* gc2_w   = (const float*)d_in[19];
    const float* gc2_b   = (const float*)d_in[20];
    const float* out_w   = (const float*)d_in[21];
    const float* out_b   = (const float*)d_in[22];

    float* ws    = (float*)d_ws;
    float* lh    = ws;                  // 524288
    float* e1    = lh + 524288;         // 262144
    float* e2    = e1 + 262144;         // 262144
    float* nrmss = e2 + 262144;         // 8192
    float* h1g   = nrmss + 8192;        // 81920
    unsigned short* amxb    = (unsigned short*)(h1g + 81920);  // 4194304
    unsigned short* adjmixb = amxb + 4194304;                  // 4194304
    unsigned short* WbT     = adjmixb + 4194304;               // 262144
    unsigned short* rgT     = WbT + 262144;                    // 524288

    fused1_kernel<<<544, 256, 0, stream>>>(
        x, Wih, Whh, bih, bhh, W1, W2, lh, e1, e2,
        conv_w, conv_b, convl_w, convl_b, gc1_w, rgT, Wb, WbT, nrmss);
    amx_kernel<<<dim3(8, 8, 16), 256, 0, stream>>>(e1, e2, b1, V, bv,
                                                   amxb, nrmss);
    gemm_adjmix_h1<<<dim3(16, 16), 256, 0, stream>>>(
        amxb, WbT, wb, adj, nrmss, adjmixb, rgT, gc1_b, gc2_w, h1g);
    ospout_kernel<<<512, 256, 0, stream>>>(adjmixb, h1g, gc2_b, lh,
                                           out_w, out_b, (float*)d_out);
}